// Round 1
// baseline (342.839 us; speedup 1.0000x reference)
//
#include <hip/hip_runtime.h>
#include <hip/hip_bf16.h>

// Fused attention block: B=4, N=2048, C=1024, H=16, D=64
//   q/k/v = x@W{q,k,v}; attn = softmax(qk^T/8); out = (attn@v)@Wo + bo
// Strategy: cast to bf16, MFMA GEMMs (16x16x32), flash-style attention.

typedef __bf16 bf16x8 __attribute__((ext_vector_type(8)));   // 4 VGPRs, MFMA A/B frag
typedef float  f32x4  __attribute__((ext_vector_type(4)));   // MFMA C/D frag

__device__ __forceinline__ f32x4 mfma16(bf16x8 a, bf16x8 b, f32x4 c) {
    return __builtin_amdgcn_mfma_f32_16x16x32_bf16(a, b, c, 0, 0, 0);
}

__device__ __forceinline__ unsigned short f2bf(float f) {
    unsigned u = __builtin_bit_cast(unsigned, f);
    u += 0x7fffu + ((u >> 16) & 1u);            // round-to-nearest-even
    return (unsigned short)(u >> 16);
}

__device__ __forceinline__ void gload16(const ushort* g, ushort* l) {
    // async global->LDS, 16B per lane; LDS dest is wave-uniform base + lane*16
    __builtin_amdgcn_global_load_lds(
        (const __attribute__((address_space(1))) void*)g,
        (__attribute__((address_space(3))) void*)l, 16, 0, 0);
}

// ---------------- cast fp32 -> bf16 (vectorized) ----------------
__global__ void cast_bf16_kernel(const float4* __restrict__ in,
                                 ushort4* __restrict__ out, int n4) {
    int i = blockIdx.x * blockDim.x + threadIdx.x;
    if (i < n4) {
        float4 f = in[i];
        ushort4 r;
        r.x = f2bf(f.x); r.y = f2bf(f.y); r.z = f2bf(f.z); r.w = f2bf(f.w);
        out[i] = r;
    }
}

// ---------------- transpose + cast weights: Wt[n][k] = bf16(W[k][n]) --------
__global__ void transpose_cast_kernel(const float* __restrict__ Wq,
                                      const float* __restrict__ Wk,
                                      const float* __restrict__ Wv,
                                      const float* __restrict__ Wo,
                                      ushort* __restrict__ out) {
    __shared__ float tile[32][33];
    const int z = blockIdx.z;
    const float* W = (z == 0) ? Wq : (z == 1) ? Wk : (z == 2) ? Wv : Wo;
    ushort* o = out + (size_t)z * 1024 * 1024;
    const int k0 = blockIdx.x * 32, n0 = blockIdx.y * 32;
    const int tx = threadIdx.x, ty = threadIdx.y;   // (32,8)
#pragma unroll
    for (int i = 0; i < 4; i++)
        tile[ty + 8 * i][tx] = W[(size_t)(k0 + ty + 8 * i) * 1024 + n0 + tx];
    __syncthreads();
#pragma unroll
    for (int i = 0; i < 4; i++)
        o[(size_t)(n0 + ty + 8 * i) * 1024 + k0 + tx] = f2bf(tile[tx][ty + 8 * i]);
}

// ---------------- 128x128 MFMA GEMM, K=1024, BK=32 (m97-style) ----------------
// A [8192][1024] bf16 row-major; Bt [1024][1024] bf16 = B^T (row n = out col).
// MODE 0: out bf16 in [B,H,N,D] layout, z = blockIdx.z selects {Wq,Wk,Wv}/{Q,K,V}
// MODE 1: out fp32 row-major [8192][1024] + bias
template <int MODE>
__global__ __launch_bounds__(256) void gemm128(const ushort* __restrict__ A,
                                               const ushort* __restrict__ Bt,
                                               ushort* __restrict__ outB,
                                               float* __restrict__ outF,
                                               const float* __restrict__ bias) {
    __shared__ ushort As[128 * 32];
    __shared__ ushort Bs[128 * 32];
    const int tid = threadIdx.x;
    const int lane = tid & 63;
    const int wid = tid >> 6;
    const int wm = wid >> 1, wn = wid & 1;
    const int m0 = blockIdx.x * 128;
    const int n0 = blockIdx.y * 128;
    if (MODE == 0) Bt += (size_t)blockIdx.z * (1024 * 1024);

    f32x4 acc[4][4] = {};

    for (int k0 = 0; k0 < 1024; k0 += 32) {
#pragma unroll
        for (int it = 0; it < 2; ++it) {
            int e = (it * 256 + tid) * 8;      // LDS elem offset, lane-contiguous
            int r = e >> 5, c = e & 31;
            gload16(&A[(size_t)(m0 + r) * 1024 + k0 + c], &As[e]);
            gload16(&Bt[(size_t)(n0 + r) * 1024 + k0 + c], &Bs[e]);
        }
        __syncthreads();   // drains vmcnt before barrier

        bf16x8 a[4], b[4];
#pragma unroll
        for (int i = 0; i < 4; i++) {
            a[i] = *(const bf16x8*)&As[(wm * 64 + i * 16 + (lane & 15)) * 32 + (lane >> 4) * 8];
            b[i] = *(const bf16x8*)&Bs[(wn * 64 + i * 16 + (lane & 15)) * 32 + (lane >> 4) * 8];
        }
#pragma unroll
        for (int i = 0; i < 4; i++)
#pragma unroll
            for (int j = 0; j < 4; j++)
                acc[i][j] = mfma16(a[i], b[j], acc[i][j]);
        __syncthreads();
    }

    // epilogue: C/D layout row=(lane>>4)*4+reg, col=lane&15
#pragma unroll
    for (int i = 0; i < 4; i++) {
        int row_b = m0 + wm * 64 + i * 16 + ((lane >> 4) * 4);
#pragma unroll
        for (int j = 0; j < 4; j++) {
            int col = n0 + wn * 64 + j * 16 + (lane & 15);
#pragma unroll
            for (int r = 0; r < 4; r++) {
                int row = row_b + r;
                float v = acc[i][j][r];
                if (MODE == 0) {
                    ushort* o = outB + (size_t)blockIdx.z * (8192ull * 1024);
                    int b = row >> 11, n = row & 2047, h = col >> 6, d = col & 63;
                    o[((((size_t)(b * 16 + h)) * 2048 + n) << 6) + d] = f2bf(v);
                } else {
                    outF[(size_t)row * 1024 + col] = v + bias[col];
                }
            }
        }
    }
}

// ---------------- flash attention ----------------
// grid (32 q-tiles, 64 bh). block 256 = 4 waves; wave owns 16 q rows.
// Q,K,V in [B,H,N,D] bf16. O written bf16 in [B,N,H*D] (= [8192][1024]).
#define ATT_SCALE 0.125f

__global__ __launch_bounds__(256) void attn_kernel(const ushort* __restrict__ Q,
                                                   const ushort* __restrict__ K,
                                                   const ushort* __restrict__ V,
                                                   ushort* __restrict__ O) {
    __shared__ ushort Ks[64 * 64];      // [key][d], XOR-swizzled
    __shared__ ushort Vs[64 * 64];      // [d][key] (V^T), XOR-swizzled
    __shared__ ushort Ps[4][16 * 64];   // per-wave P, XOR-swizzled
    const int tid = threadIdx.x;
    const int lane = tid & 63;
    const int wid = tid >> 6;
    const int qt = blockIdx.x;
    const int bh = blockIdx.y;
    const size_t base = (size_t)bh * (2048 * 64);

    // Q fragments: A-layout row=lane&15, k=(lane>>4)*8+j (+32 for second frag)
    const int qrow = qt * 64 + wid * 16 + (lane & 15);
    bf16x8 qf[2];
    qf[0] = *(const bf16x8*)&Q[base + (size_t)qrow * 64 + (lane >> 4) * 8];
    qf[1] = *(const bf16x8*)&Q[base + (size_t)qrow * 64 + 32 + (lane >> 4) * 8];

    f32x4 o[4] = {};
    float mrow[4] = {-1e30f, -1e30f, -1e30f, -1e30f};
    float lrow[4] = {0.f, 0.f, 0.f, 0.f};

    char* KsB = (char*)Ks;
    char* VsB = (char*)Vs;
    char* PsB = (char*)Ps[wid];

    for (int kt = 0; kt < 2048; kt += 64) {
        // ---- stage K (row-major, swizzled) and V^T (swizzled) ----
#pragma unroll
        for (int it = 0; it < 2; ++it) {
            int ci = it * 256 + tid;
            int key = ci >> 3, d0 = (ci & 7) * 8;
            uint4 kv = *(const uint4*)&K[base + (size_t)(kt + key) * 64 + d0];
            int byt = (key * 128 + d0 * 2) ^ ((key & 7) << 4);
            *(uint4*)(KsB + byt) = kv;

            int key2 = ci & 63;             // lane-distinct keys -> 2-way writes
            int d0v = (ci >> 6) * 8;
            uint4 vv = *(const uint4*)&V[base + (size_t)(kt + key2) * 64 + d0v];
            const ushort* vs = (const ushort*)&vv;
#pragma unroll
            for (int j = 0; j < 8; j++) {
                int d = d0v + j;
                int b2 = (d * 128 + key2 * 2) ^ ((d & 7) << 4);
                *(ushort*)(VsB + b2) = vs[j];
            }
        }
        __syncthreads();

        // ---- S = Q K^T  (16 q-rows x 64 keys per wave) ----
        f32x4 s[4] = {};
#pragma unroll
        for (int kb = 0; kb < 4; ++kb) {
#pragma unroll
            for (int ks = 0; ks < 2; ++ks) {
                int key = kb * 16 + (lane & 15);
                int d0 = ks * 32 + (lane >> 4) * 8;
                int byt = (key * 128 + d0 * 2) ^ ((key & 7) << 4);
                bf16x8 kf = *(const bf16x8*)(KsB + byt);
                s[kb] = mfma16(qf[ks], kf, s[kb]);
            }
        }

        // ---- online softmax, rows q=(lane>>4)*4+r; 16-lane-group reductions --
#pragma unroll
        for (int r = 0; r < 4; ++r) {
            float sv0 = s[0][r] * ATT_SCALE, sv1 = s[1][r] * ATT_SCALE;
            float sv2 = s[2][r] * ATT_SCALE, sv3 = s[3][r] * ATT_SCALE;
            float mx = fmaxf(fmaxf(sv0, sv1), fmaxf(sv2, sv3));
            mx = fmaxf(mx, __shfl_xor(mx, 1));
            mx = fmaxf(mx, __shfl_xor(mx, 2));
            mx = fmaxf(mx, __shfl_xor(mx, 4));
            mx = fmaxf(mx, __shfl_xor(mx, 8));
            float mn = fmaxf(mrow[r], mx);
            float fr = __expf(mrow[r] - mn);
            mrow[r] = mn;
            float p0 = __expf(sv0 - mn), p1 = __expf(sv1 - mn);
            float p2 = __expf(sv2 - mn), p3 = __expf(sv3 - mn);
            float rs = p0 + p1 + p2 + p3;
            rs += __shfl_xor(rs, 1);
            rs += __shfl_xor(rs, 2);
            rs += __shfl_xor(rs, 4);
            rs += __shfl_xor(rs, 8);
            lrow[r] = lrow[r] * fr + rs;
#pragma unroll
            for (int cb = 0; cb < 4; ++cb) o[cb][r] *= fr;

            // scatter P to per-wave LDS (swizzled, u16)
            int q = (lane >> 4) * 4 + r;
            int key0 = lane & 15;
            float pv[4] = {p0, p1, p2, p3};
#pragma unroll
            for (int kb = 0; kb < 4; ++kb) {
                int key = kb * 16 + key0;
                int b2 = (q * 128 + key * 2) ^ ((q & 7) << 4);
                *(ushort*)(PsB + b2) = f2bf(pv[kb]);
            }
        }
        // wave-private P: in-wave RAW through LDS, compiler inserts lgkmcnt wait

        // ---- O += P V ----
        bf16x8 pa[2];
#pragma unroll
        for (int ks = 0; ks < 2; ++ks) {
            int q = lane & 15;
            int k0b = (ks * 32 + (lane >> 4) * 8) * 2;
            int byt = (q * 128 + k0b) ^ ((q & 7) << 4);
            pa[ks] = *(const bf16x8*)(PsB + byt);
        }
#pragma unroll
        for (int cb = 0; cb < 4; ++cb) {
#pragma unroll
            for (int ks = 0; ks < 2; ++ks) {
                int d = cb * 16 + (lane & 15);
                int byt = (d * 128 + (ks * 32 + (lane >> 4) * 8) * 2) ^ ((d & 7) << 4);
                bf16x8 vf = *(const bf16x8*)(VsB + byt);
                o[cb] = mfma16(pa[ks], vf, o[cb]);
            }
        }
        __syncthreads();   // all LDS reads done before next tile's staging
    }

    // ---- epilogue: O /= l, write bf16 [B,N,H*D] ----
    const int b = bh >> 4, h = bh & 15;
#pragma unroll
    for (int r = 0; r < 4; ++r) {
        float inv = 1.0f / lrow[r];
        int row = qt * 64 + wid * 16 + (lane >> 4) * 4 + r;
#pragma unroll
        for (int cb = 0; cb < 4; ++cb) {
            int col = h * 64 + cb * 16 + (lane & 15);
            O[((size_t)(b * 2048 + row)) * 1024 + col] = f2bf(o[cb][r] * inv);
        }
    }
}

// ---------------- launch ----------------
extern "C" void kernel_launch(void* const* d_in, const int* in_sizes, int n_in,
                              void* d_out, int out_size, void* d_ws, size_t ws_size,
                              hipStream_t stream) {
    const float* x  = (const float*)d_in[0];
    const float* Wq = (const float*)d_in[1];
    const float* Wk = (const float*)d_in[2];
    const float* Wv = (const float*)d_in[3];
    const float* Wo = (const float*)d_in[4];
    const float* bo = (const float*)d_in[5];
    float* out = (float*)d_out;

    // workspace layout (bf16 elems): xb 8Mi | wt 4Mi | qkv 24Mi  => 72 MiB
    if (ws_size < (size_t)72 * 1024 * 1024) return;  // insufficient scratch
    ushort* ws  = (ushort*)d_ws;
    ushort* xb  = ws;
    ushort* wt  = xb + (size_t)8 * 1024 * 1024;
    ushort* qkv = wt + (size_t)4 * 1024 * 1024;
    ushort* ao  = xb;   // reuse xb after QKV GEMM consumed it

    // 1) x -> bf16
    cast_bf16_kernel<<<8192, 256, 0, stream>>>((const float4*)x, (ushort4*)xb,
                                               2 * 1024 * 1024);
    // 2) weights -> bf16, transposed
    transpose_cast_kernel<<<dim3(32, 32, 4), dim3(32, 8), 0, stream>>>(Wq, Wk, Wv, Wo, wt);
    // 3) Q,K,V = x @ W{q,k,v}  (bf16 out, [B,H,N,D])
    gemm128<0><<<dim3(64, 8, 3), 256, 0, stream>>>(xb, wt, qkv, nullptr, nullptr);
    // 4) attention
    attn_kernel<<<dim3(32, 64), 256, 0, stream>>>(
        qkv, qkv + (size_t)8 * 1024 * 1024, qkv + (size_t)16 * 1024 * 1024, ao);
    // 5) out = attn_out @ Wo + bo  (fp32)
    gemm128<1><<<dim3(64, 8, 1), 256, 0, stream>>>(ao, wt + (size_t)3 * 1024 * 1024,
                                                   nullptr, out, bo);
}

// Round 2
// 260.012 us; speedup vs baseline: 1.3185x; 1.3185x over previous
//
#include <hip/hip_runtime.h>
#include <hip/hip_bf16.h>

// Fused attention block: B=4, N=2048, C=1024, H=16, D=64
//   q/k/v = x@W{q,k,v}; attn = softmax(qk^T/8); out = (attn@v)@Wo + bo
// Strategy: cast to bf16, MFMA GEMMs (16x16x32), flash-style attention with
// swapped QK^T (S^T) -> in-lane softmax, cvt_pk P repack, MFMA row-sums.

typedef __bf16 bf16x8 __attribute__((ext_vector_type(8)));   // 4 VGPRs, MFMA A/B frag
typedef float  f32x4  __attribute__((ext_vector_type(4)));   // MFMA C/D frag
typedef unsigned int u32x4 __attribute__((ext_vector_type(4)));

__device__ __forceinline__ f32x4 mfma16(bf16x8 a, bf16x8 b, f32x4 c) {
    return __builtin_amdgcn_mfma_f32_16x16x32_bf16(a, b, c, 0, 0, 0);
}

__device__ __forceinline__ unsigned short f2bf(float f) {
    unsigned u = __builtin_bit_cast(unsigned, f);
    u += 0x7fffu + ((u >> 16) & 1u);            // round-to-nearest-even
    return (unsigned short)(u >> 16);
}

__device__ __forceinline__ unsigned cvt_pk_bf16(float lo, float hi) {
    unsigned r;
    asm("v_cvt_pk_bf16_f32 %0, %1, %2" : "=v"(r) : "v"(lo), "v"(hi));
    return r;   // bits[15:0]=bf16(lo), bits[31:16]=bf16(hi)
}

__device__ __forceinline__ void gload16(const ushort* g, ushort* l) {
    __builtin_amdgcn_global_load_lds(
        (const __attribute__((address_space(1))) void*)g,
        (__attribute__((address_space(3))) void*)l, 16, 0, 0);
}

// ---------------- cast fp32 -> bf16 (vectorized) ----------------
__global__ void cast_bf16_kernel(const float4* __restrict__ in,
                                 ushort4* __restrict__ out, int n4) {
    int i = blockIdx.x * blockDim.x + threadIdx.x;
    if (i < n4) {
        float4 f = in[i];
        ushort4 r;
        r.x = f2bf(f.x); r.y = f2bf(f.y); r.z = f2bf(f.z); r.w = f2bf(f.w);
        out[i] = r;
    }
}

// ---------------- transpose + cast weights: Wt[n][k] = bf16(W[k][n]) --------
__global__ void transpose_cast_kernel(const float* __restrict__ Wq,
                                      const float* __restrict__ Wk,
                                      const float* __restrict__ Wv,
                                      const float* __restrict__ Wo,
                                      ushort* __restrict__ out) {
    __shared__ float tile[32][33];
    const int z = blockIdx.z;
    const float* W = (z == 0) ? Wq : (z == 1) ? Wk : (z == 2) ? Wv : Wo;
    ushort* o = out + (size_t)z * 1024 * 1024;
    const int k0 = blockIdx.x * 32, n0 = blockIdx.y * 32;
    const int tx = threadIdx.x, ty = threadIdx.y;   // (32,8)
#pragma unroll
    for (int i = 0; i < 4; i++)
        tile[ty + 8 * i][tx] = W[(size_t)(k0 + ty + 8 * i) * 1024 + n0 + tx];
    __syncthreads();
#pragma unroll
    for (int i = 0; i < 4; i++)
        o[(size_t)(n0 + ty + 8 * i) * 1024 + k0 + tx] = f2bf(tile[tx][ty + 8 * i]);
}

// ---------------- 128x128 MFMA GEMM, K=1024, BK=32 (m97-style) ----------------
template <int MODE>
__global__ __launch_bounds__(256) void gemm128(const ushort* __restrict__ A,
                                               const ushort* __restrict__ Bt,
                                               ushort* __restrict__ outB,
                                               float* __restrict__ outF,
                                               const float* __restrict__ bias) {
    __shared__ ushort As[128 * 32];
    __shared__ ushort Bs[128 * 32];
    const int tid = threadIdx.x;
    const int lane = tid & 63;
    const int wid = tid >> 6;
    const int wm = wid >> 1, wn = wid & 1;
    const int m0 = blockIdx.x * 128;
    const int n0 = blockIdx.y * 128;
    if (MODE == 0) Bt += (size_t)blockIdx.z * (1024 * 1024);

    f32x4 acc[4][4] = {};

    for (int k0 = 0; k0 < 1024; k0 += 32) {
#pragma unroll
        for (int it = 0; it < 2; ++it) {
            int e = (it * 256 + tid) * 8;
            int r = e >> 5, c = e & 31;
            gload16(&A[(size_t)(m0 + r) * 1024 + k0 + c], &As[e]);
            gload16(&Bt[(size_t)(n0 + r) * 1024 + k0 + c], &Bs[e]);
        }
        __syncthreads();

        bf16x8 a[4], b[4];
#pragma unroll
        for (int i = 0; i < 4; i++) {
            a[i] = *(const bf16x8*)&As[(wm * 64 + i * 16 + (lane & 15)) * 32 + (lane >> 4) * 8];
            b[i] = *(const bf16x8*)&Bs[(wn * 64 + i * 16 + (lane & 15)) * 32 + (lane >> 4) * 8];
        }
#pragma unroll
        for (int i = 0; i < 4; i++)
#pragma unroll
            for (int j = 0; j < 4; j++)
                acc[i][j] = mfma16(a[i], b[j], acc[i][j]);
        __syncthreads();
    }

#pragma unroll
    for (int i = 0; i < 4; i++) {
        int row_b = m0 + wm * 64 + i * 16 + ((lane >> 4) * 4);
#pragma unroll
        for (int j = 0; j < 4; j++) {
            int col = n0 + wn * 64 + j * 16 + (lane & 15);
#pragma unroll
            for (int r = 0; r < 4; r++) {
                int row = row_b + r;
                float v = acc[i][j][r];
                if (MODE == 0) {
                    ushort* o = outB + (size_t)blockIdx.z * (8192ull * 1024);
                    int b = row >> 11, n = row & 2047, h = col >> 6, d = col & 63;
                    o[((((size_t)(b * 16 + h)) * 2048 + n) << 6) + d] = f2bf(v);
                } else {
                    outF[(size_t)row * 1024 + col] = v + bias[col];
                }
            }
        }
    }
}

// ---------------- flash attention (swapped QK^T, in-lane softmax) ----------
// grid (32 q-tiles, 64 bh). block 256 = 4 waves; wave owns 16 q rows.
// Q,K,V in [B,H,N,D] bf16. O written bf16 in [B,N,H*D] (= [8192][1024]).
#define LSCALE 0.18033688f   // (1/8) * log2(e): softmax in exp2 domain

__global__ __launch_bounds__(256) void attn_kernel(const ushort* __restrict__ Q,
                                                   const ushort* __restrict__ K,
                                                   const ushort* __restrict__ V,
                                                   ushort* __restrict__ O) {
    __shared__ ushort Ks[64 * 64];      // [key][d], XOR-swizzled
    __shared__ ushort Vs[64 * 64];      // [d][key] (V^T), XOR-swizzled
    __shared__ ushort Ps[4][16 * 64];   // per-wave 2KB: P exchange buffer
    const int tid = threadIdx.x;
    const int lane = tid & 63;
    const int wid = tid >> 6;
    const int g = lane >> 4;          // 16-lane group
    const int q16 = lane & 15;
    const int qt = blockIdx.x;
    const int bh = blockIdx.y;
    const size_t base = (size_t)bh * (2048 * 64);

    // Q fragments: B-operand layout col=lane&15 (=q), k=(lane>>4)*8+j
    const int qrow = qt * 64 + wid * 16 + q16;
    bf16x8 qf[2];
    qf[0] = *(const bf16x8*)&Q[base + (size_t)qrow * 64 + g * 8];
    qf[1] = *(const bf16x8*)&Q[base + (size_t)qrow * 64 + 32 + g * 8];

    // ones vector (B-frag) for MFMA row-sums
    bf16x8 onesb;
#pragma unroll
    for (int i = 0; i < 8; i++) onesb[i] = (__bf16)1.0f;

    f32x4 o[4] = {};
    f32x4 lacc = {};                  // row-sums of P, o-layout rows
    float m_run = -1e30f;             // per-lane running max (q = lane&15)

    char* KsB = (char*)Ks;
    char* VsB = (char*)Vs;
    char* PsB = (char*)Ps[wid];

    for (int kt = 0; kt < 2048; kt += 64) {
        // ---- stage K (row-major, swizzled) and V^T (swizzled) ----
#pragma unroll
        for (int it = 0; it < 2; ++it) {
            int ci = it * 256 + tid;
            int key = ci >> 3, d0 = (ci & 7) * 8;
            uint4 kv = *(const uint4*)&K[base + (size_t)(kt + key) * 64 + d0];
            int byt = (key * 128 + d0 * 2) ^ ((key & 7) << 4);
            *(uint4*)(KsB + byt) = kv;

            int key2 = ci & 63;
            int d0v = (ci >> 6) * 8;
            uint4 vv = *(const uint4*)&V[base + (size_t)(kt + key2) * 64 + d0v];
            const ushort* vs = (const ushort*)&vv;
#pragma unroll
            for (int j = 0; j < 8; j++) {
                int d = d0v + j;
                int b2 = (d * 128 + key2 * 2) ^ ((d & 7) << 4);
                *(ushort*)(VsB + b2) = vs[j];
            }
        }
        __syncthreads();

        // ---- S^T = K Q^T : s[kb][r] = S[q=lane&15][key = kb*16 + 4g + r] ----
        f32x4 s[4] = {};
#pragma unroll
        for (int kb = 0; kb < 4; ++kb) {
#pragma unroll
            for (int ks = 0; ks < 2; ++ks) {
                int key = kb * 16 + q16;
                int d0 = ks * 32 + g * 8;
                int byt = (key * 128 + d0 * 2) ^ ((key & 7) << 4);
                bf16x8 kf = *(const bf16x8*)(KsB + byt);
                s[kb] = mfma16(kf, qf[ks], s[kb]);   // swapped: K as A, Q as B
            }
        }

        // ---- in-lane online softmax over the 16 keys this lane holds ----
        float t[4][4];
#pragma unroll
        for (int kb = 0; kb < 4; ++kb)
#pragma unroll
            for (int r = 0; r < 4; ++r) t[kb][r] = s[kb][r] * LSCALE;

        float mx = fmaxf(fmaxf(fmaxf(t[0][0], t[0][1]), fmaxf(t[0][2], t[0][3])),
                         fmaxf(fmaxf(t[1][0], t[1][1]), fmaxf(t[1][2], t[1][3])));
        mx = fmaxf(mx, fmaxf(fmaxf(fmaxf(t[2][0], t[2][1]), fmaxf(t[2][2], t[2][3])),
                             fmaxf(fmaxf(t[3][0], t[3][1]), fmaxf(t[3][2], t[3][3]))));
        mx = fmaxf(mx, __shfl_xor(mx, 16));
        mx = fmaxf(mx, __shfl_xor(mx, 32));
        float mn = fmaxf(m_run, mx);
        float fr = __builtin_amdgcn_exp2f(m_run - mn);
        m_run = mn;

        // P = exp2(t - mn), packed to bf16 pairs: w[kb] = {p0p1, p2p3}
        unsigned w[4][2];
#pragma unroll
        for (int kb = 0; kb < 4; ++kb) {
            float p0 = __builtin_amdgcn_exp2f(t[kb][0] - mn);
            float p1 = __builtin_amdgcn_exp2f(t[kb][1] - mn);
            float p2 = __builtin_amdgcn_exp2f(t[kb][2] - mn);
            float p3 = __builtin_amdgcn_exp2f(t[kb][3] - mn);
            w[kb][0] = cvt_pk_bf16(p0, p1);
            w[kb][1] = cvt_pk_bf16(p2, p3);
        }

        // ---- P exchange: C-layout -> A-frag layout via wave-private LDS ----
        // chunk layout per lane: chunk0=[w0,w2], chunk1=[w1,w3]; addr swizzled.
        {
            u32x4 c0 = {w[0][0], w[0][1], w[2][0], w[2][1]};
            u32x4 c1 = {w[1][0], w[1][1], w[3][0], w[3][1]};
            *(u32x4*)(PsB + ((lane * 32 + 0)  ^ ((lane & 7) << 4))) = c0;
            *(u32x4*)(PsB + ((lane * 32 + 16) ^ ((lane & 7) << 4))) = c1;
        }
        int s1 = q16 + 32 * (g & 1);          // first source lane
        int ch = (g >> 1) * 16;               // chunk byte offset
        u32x4 r1 = *(const u32x4*)(PsB + ((s1 * 32 + ch) ^ ((s1 & 7) << 4)));
        u32x4 r2 = *(const u32x4*)(PsB + (((s1 + 16) * 32 + ch) ^ (((s1 + 16) & 7) << 4)));
        bf16x8 pa[2];
        {
            u32x4 p0 = {r1.x, r1.y, r2.x, r2.y};   // keys ks*32+8g+0..7, kb=g>>1 base
            u32x4 p1 = {r1.z, r1.w, r2.z, r2.w};   // kb = 2+(g>>1)
            pa[0] = __builtin_bit_cast(bf16x8, p0);
            pa[1] = __builtin_bit_cast(bf16x8, p1);
        }

        // ---- rescale o/lacc (o-layout rows q' = 4g + r), accumulate ----
        float fro[4];
#pragma unroll
        for (int r = 0; r < 4; ++r) fro[r] = __shfl(fr, g * 4 + r);
#pragma unroll
        for (int cb = 0; cb < 4; ++cb)
#pragma unroll
            for (int r = 0; r < 4; ++r) o[cb][r] *= fro[r];
#pragma unroll
        for (int r = 0; r < 4; ++r) lacc[r] *= fro[r];

        lacc = mfma16(pa[0], onesb, lacc);    // row-sums via ones-MFMA
        lacc = mfma16(pa[1], onesb, lacc);

        // ---- O += P V ----
#pragma unroll
        for (int cb = 0; cb < 4; ++cb) {
#pragma unroll
            for (int ks = 0; ks < 2; ++ks) {
                int d = cb * 16 + q16;
                int byt = (d * 128 + (ks * 32 + g * 8) * 2) ^ ((d & 7) << 4);
                bf16x8 vf = *(const bf16x8*)(VsB + byt);
                o[cb] = mfma16(pa[ks], vf, o[cb]);
            }
        }
        __syncthreads();
    }

    // ---- epilogue: O /= l, write bf16 [B,N,H*D] ----
    const int b = bh >> 4, h = bh & 15;
#pragma unroll
    for (int r = 0; r < 4; ++r) {
        float inv = 1.0f / lacc[r];
        int row = qt * 64 + wid * 16 + g * 4 + r;
#pragma unroll
        for (int cb = 0; cb < 4; ++cb) {
            int col = h * 64 + cb * 16 + q16;
            O[((size_t)(b * 2048 + row)) * 1024 + col] = f2bf(o[cb][r] * inv);
        }
    }
}

// ---------------- launch ----------------
extern "C" void kernel_launch(void* const* d_in, const int* in_sizes, int n_in,
                              void* d_out, int out_size, void* d_ws, size_t ws_size,
                              hipStream_t stream) {
    const float* x  = (const float*)d_in[0];
    const float* Wq = (const float*)d_in[1];
    const float* Wk = (const float*)d_in[2];
    const float* Wv = (const float*)d_in[3];
    const float* Wo = (const float*)d_in[4];
    const float* bo = (const float*)d_in[5];
    float* out = (float*)d_out;

    if (ws_size < (size_t)72 * 1024 * 1024) return;
    ushort* ws  = (ushort*)d_ws;
    ushort* xb  = ws;
    ushort* wt  = xb + (size_t)8 * 1024 * 1024;
    ushort* qkv = wt + (size_t)4 * 1024 * 1024;
    ushort* ao  = xb;   // reuse xb after QKV GEMM consumed it

    cast_bf16_kernel<<<8192, 256, 0, stream>>>((const float4*)x, (ushort4*)xb,
                                               2 * 1024 * 1024);
    transpose_cast_kernel<<<dim3(32, 32, 4), dim3(32, 8), 0, stream>>>(Wq, Wk, Wv, Wo, wt);
    gemm128<0><<<dim3(64, 8, 3), 256, 0, stream>>>(xb, wt, qkv, nullptr, nullptr);
    attn_kernel<<<dim3(32, 64), 256, 0, stream>>>(
        qkv, qkv + (size_t)8 * 1024 * 1024, qkv + (size_t)16 * 1024 * 1024, ao);
    gemm128<1><<<dim3(64, 8, 1), 256, 0, stream>>>(ao, wt + (size_t)3 * 1024 * 1024,
                                                   nullptr, out, bo);
}

// Round 4
// 250.024 us; speedup vs baseline: 1.3712x; 1.0399x over previous
//
#include <hip/hip_runtime.h>
#include <hip/hip_bf16.h>

// Fused attention block: B=4, N=2048, C=1024, H=16, D=64
//   q/k/v = x@W{q,k,v}; attn = softmax(qk^T/8); out = (attn@v)@Wo + bo
// Strategy: cast to bf16, MFMA GEMMs (16x16x32), flash-style attention with
// swapped QK^T (S^T) -> in-lane softmax, 128 q-rows/block (2 subtiles/wave),
// XCD-chunked block swizzle. K staged via explicit ds_write (round-2 proven);
// P-exchange fenced against compiler reordering (in-wave LDS RAW).

typedef __bf16 bf16x8 __attribute__((ext_vector_type(8)));   // 4 VGPRs, MFMA A/B frag
typedef float  f32x4  __attribute__((ext_vector_type(4)));   // MFMA C/D frag
typedef unsigned int u32x4 __attribute__((ext_vector_type(4)));

__device__ __forceinline__ f32x4 mfma16(bf16x8 a, bf16x8 b, f32x4 c) {
    return __builtin_amdgcn_mfma_f32_16x16x32_bf16(a, b, c, 0, 0, 0);
}

__device__ __forceinline__ unsigned short f2bf(float f) {
    unsigned u = __builtin_bit_cast(unsigned, f);
    u += 0x7fffu + ((u >> 16) & 1u);            // round-to-nearest-even
    return (unsigned short)(u >> 16);
}

__device__ __forceinline__ unsigned cvt_pk_bf16(float lo, float hi) {
    unsigned r;
    asm("v_cvt_pk_bf16_f32 %0, %1, %2" : "=v"(r) : "v"(lo), "v"(hi));
    return r;   // bits[15:0]=bf16(lo), bits[31:16]=bf16(hi)
}

__device__ __forceinline__ void gload16(const ushort* g, ushort* l) {
    __builtin_amdgcn_global_load_lds(
        (const __attribute__((address_space(1))) void*)g,
        (__attribute__((address_space(3))) void*)l, 16, 0, 0);
}

// ---------------- cast fp32 -> bf16 (vectorized) ----------------
__global__ void cast_bf16_kernel(const float4* __restrict__ in,
                                 ushort4* __restrict__ out, int n4) {
    int i = blockIdx.x * blockDim.x + threadIdx.x;
    if (i < n4) {
        float4 f = in[i];
        ushort4 r;
        r.x = f2bf(f.x); r.y = f2bf(f.y); r.z = f2bf(f.z); r.w = f2bf(f.w);
        out[i] = r;
    }
}

// ---------------- transpose + cast weights: Wt[n][k] = bf16(W[k][n]) --------
__global__ void transpose_cast_kernel(const float* __restrict__ Wq,
                                      const float* __restrict__ Wk,
                                      const float* __restrict__ Wv,
                                      const float* __restrict__ Wo,
                                      ushort* __restrict__ out) {
    __shared__ float tile[32][33];
    const int z = blockIdx.z;
    const float* W = (z == 0) ? Wq : (z == 1) ? Wk : (z == 2) ? Wv : Wo;
    ushort* o = out + (size_t)z * 1024 * 1024;
    const int k0 = blockIdx.x * 32, n0 = blockIdx.y * 32;
    const int tx = threadIdx.x, ty = threadIdx.y;   // (32,8)
#pragma unroll
    for (int i = 0; i < 4; i++)
        tile[ty + 8 * i][tx] = W[(size_t)(k0 + ty + 8 * i) * 1024 + n0 + tx];
    __syncthreads();
#pragma unroll
    for (int i = 0; i < 4; i++)
        o[(size_t)(n0 + ty + 8 * i) * 1024 + k0 + tx] = f2bf(tile[tx][ty + 8 * i]);
}

// ---------------- 128x128 MFMA GEMM, K=1024, BK=32 (m97-style) ----------------
template <int MODE>
__global__ __launch_bounds__(256) void gemm128(const ushort* __restrict__ A,
                                               const ushort* __restrict__ Bt,
                                               ushort* __restrict__ outB,
                                               float* __restrict__ outF,
                                               const float* __restrict__ bias) {
    __shared__ ushort As[128 * 32];
    __shared__ ushort Bs[128 * 32];
    const int tid = threadIdx.x;
    const int lane = tid & 63;
    const int wid = tid >> 6;
    const int wm = wid >> 1, wn = wid & 1;
    const int m0 = blockIdx.x * 128;
    const int n0 = blockIdx.y * 128;
    if (MODE == 0) Bt += (size_t)blockIdx.z * (1024 * 1024);

    f32x4 acc[4][4] = {};

    for (int k0 = 0; k0 < 1024; k0 += 32) {
#pragma unroll
        for (int it = 0; it < 2; ++it) {
            int e = (it * 256 + tid) * 8;
            int r = e >> 5, c = e & 31;
            gload16(&A[(size_t)(m0 + r) * 1024 + k0 + c], &As[e]);
            gload16(&Bt[(size_t)(n0 + r) * 1024 + k0 + c], &Bs[e]);
        }
        __syncthreads();

        bf16x8 a[4], b[4];
#pragma unroll
        for (int i = 0; i < 4; i++) {
            a[i] = *(const bf16x8*)&As[(wm * 64 + i * 16 + (lane & 15)) * 32 + (lane >> 4) * 8];
            b[i] = *(const bf16x8*)&Bs[(wn * 64 + i * 16 + (lane & 15)) * 32 + (lane >> 4) * 8];
        }
#pragma unroll
        for (int i = 0; i < 4; i++)
#pragma unroll
            for (int j = 0; j < 4; j++)
                acc[i][j] = mfma16(a[i], b[j], acc[i][j]);
        __syncthreads();
    }

#pragma unroll
    for (int i = 0; i < 4; i++) {
        int row_b = m0 + wm * 64 + i * 16 + ((lane >> 4) * 4);
#pragma unroll
        for (int j = 0; j < 4; j++) {
            int col = n0 + wn * 64 + j * 16 + (lane & 15);
#pragma unroll
            for (int r = 0; r < 4; r++) {
                int row = row_b + r;
                float v = acc[i][j][r];
                if (MODE == 0) {
                    ushort* o = outB + (size_t)blockIdx.z * (8192ull * 1024);
                    int b = row >> 11, n = row & 2047, h = col >> 6, d = col & 63;
                    o[((((size_t)(b * 16 + h)) * 2048 + n) << 6) + d] = f2bf(v);
                } else {
                    outF[(size_t)row * 1024 + col] = v + bias[col];
                }
            }
        }
    }
}

// ---------------- flash attention ----------------
// grid 1024 (XCD-chunk swizzled -> (qt, bh)). block 256 = 4 waves.
// Block owns 128 q-rows; wave owns 32 (two 16-row subtiles u=0,1).
// Q,K,V in [B,H,N,D] bf16. O written bf16 in [B,N,H*D] (= [8192][1024]).
#define LSCALE 0.18033688f   // (1/8) * log2(e): softmax in exp2 domain

__global__ __launch_bounds__(256) void attn_kernel(const ushort* __restrict__ Q,
                                                   const ushort* __restrict__ K,
                                                   const ushort* __restrict__ V,
                                                   ushort* __restrict__ O) {
    __shared__ ushort Ks[64 * 64];        // [key][d], XOR-swizzled
    __shared__ ushort Vs[64 * 64];        // [d][key] (V^T), XOR-swizzled
    __shared__ ushort Ps[4][2][1024];     // per-wave, per-subtile P exchange
    const int tid = threadIdx.x;
    const int lane = tid & 63;
    const int wid = tid >> 6;
    const int g = lane >> 4;          // 16-lane group
    const int q16 = lane & 15;
    const int bid = blockIdx.x;
    const int swz = (bid & 7) * 128 + (bid >> 3);   // XCD-chunked (1024 % 8 == 0)
    const int bh = swz >> 4;
    const int qt = swz & 15;
    const size_t base = (size_t)bh * (2048 * 64);

    // Q fragments (B-operand layout col=q16, k=g*8+j), two subtiles per wave
    const int qr0 = qt * 128 + wid * 32 + q16;
    bf16x8 qf[2][2];
#pragma unroll
    for (int u = 0; u < 2; ++u)
#pragma unroll
        for (int ks = 0; ks < 2; ++ks)
            qf[u][ks] = *(const bf16x8*)&Q[base + (size_t)(qr0 + u * 16) * 64 + ks * 32 + g * 8];

    bf16x8 onesb;
#pragma unroll
    for (int i = 0; i < 8; i++) onesb[i] = (__bf16)1.0f;

    f32x4 o[2][4] = {};
    f32x4 lacc[2] = {};
    float m_run[2] = {-1e30f, -1e30f};

    char* KsB = (char*)Ks;
    char* VsB = (char*)Vs;

    for (int kt = 0; kt < 2048; kt += 64) {
        // ---- stage K (row-major, swizzled) and V^T (swizzled) ----
#pragma unroll
        for (int it = 0; it < 2; ++it) {
            int ci = it * 256 + tid;
            int key = ci >> 3, d0 = (ci & 7) * 8;
            uint4 kv = *(const uint4*)&K[base + (size_t)(kt + key) * 64 + d0];
            int byt = (key * 128 + d0 * 2) ^ ((key & 7) << 4);
            *(uint4*)(KsB + byt) = kv;

            int key2 = ci & 63;
            int d0v = (ci >> 6) * 8;
            uint4 vv = *(const uint4*)&V[base + (size_t)(kt + key2) * 64 + d0v];
            const ushort* vs = (const ushort*)&vv;
#pragma unroll
            for (int j = 0; j < 8; j++) {
                int d = d0v + j;
                int b2 = (d * 128 + key2 * 2) ^ ((d & 7) << 4);
                *(ushort*)(VsB + b2) = vs[j];
            }
        }
        __syncthreads();

        // ---- S^T = K Q^T : s[u][kb][r] = S[q=q16][key=kb*16+4g+r] ----
        f32x4 s[2][4] = {};
#pragma unroll
        for (int kb = 0; kb < 4; ++kb) {
#pragma unroll
            for (int ks = 0; ks < 2; ++ks) {
                int key = kb * 16 + q16;
                int d0 = ks * 32 + g * 8;
                int byt = (key * 128 + d0 * 2) ^ ((key & 7) << 4);
                bf16x8 kf = *(const bf16x8*)(KsB + byt);
                s[0][kb] = mfma16(kf, qf[0][ks], s[0][kb]);
                s[1][kb] = mfma16(kf, qf[1][ks], s[1][kb]);
            }
        }

        bf16x8 pa[2][2];
#pragma unroll
        for (int u = 0; u < 2; ++u) {
            // ---- in-lane online softmax over this lane's 16 keys ----
            float t[4][4];
#pragma unroll
            for (int kb = 0; kb < 4; ++kb)
#pragma unroll
                for (int r = 0; r < 4; ++r) t[kb][r] = s[u][kb][r] * LSCALE;

            float mx = fmaxf(fmaxf(fmaxf(t[0][0], t[0][1]), fmaxf(t[0][2], t[0][3])),
                             fmaxf(fmaxf(t[1][0], t[1][1]), fmaxf(t[1][2], t[1][3])));
            mx = fmaxf(mx, fmaxf(fmaxf(fmaxf(t[2][0], t[2][1]), fmaxf(t[2][2], t[2][3])),
                                 fmaxf(fmaxf(t[3][0], t[3][1]), fmaxf(t[3][2], t[3][3]))));
            mx = fmaxf(mx, __shfl_xor(mx, 16));
            mx = fmaxf(mx, __shfl_xor(mx, 32));
            float mn = fmaxf(m_run[u], mx);
            float fr = __builtin_amdgcn_exp2f(m_run[u] - mn);
            m_run[u] = mn;

            unsigned w[4][2];
#pragma unroll
            for (int kb = 0; kb < 4; ++kb) {
                float p0 = __builtin_amdgcn_exp2f(t[kb][0] - mn);
                float p1 = __builtin_amdgcn_exp2f(t[kb][1] - mn);
                float p2 = __builtin_amdgcn_exp2f(t[kb][2] - mn);
                float p3 = __builtin_amdgcn_exp2f(t[kb][3] - mn);
                w[kb][0] = cvt_pk_bf16(p0, p1);
                w[kb][1] = cvt_pk_bf16(p2, p3);
            }

            // ---- P exchange: C-layout -> A-frag layout via wave-private LDS.
            // In-wave cross-lane RAW through LDS: fence so the compiler cannot
            // reorder the reads above the writes (DS pipe is in-order per wave).
            char* PsB = (char*)Ps[wid][u];
            {
                u32x4 c0 = {w[0][0], w[0][1], w[2][0], w[2][1]};
                u32x4 c1 = {w[1][0], w[1][1], w[3][0], w[3][1]};
                *(u32x4*)(PsB + ((lane * 32 + 0)  ^ ((lane & 7) << 4))) = c0;
                *(u32x4*)(PsB + ((lane * 32 + 16) ^ ((lane & 7) << 4))) = c1;
            }
            asm volatile("" ::: "memory");
            __builtin_amdgcn_sched_barrier(0);
            int s1 = q16 + 32 * (g & 1);
            int ch = (g >> 1) * 16;
            u32x4 r1 = *(const u32x4*)(PsB + ((s1 * 32 + ch) ^ ((s1 & 7) << 4)));
            u32x4 r2 = *(const u32x4*)(PsB + (((s1 + 16) * 32 + ch) ^ (((s1 + 16) & 7) << 4)));
            asm volatile("" ::: "memory");
            {
                u32x4 p0 = {r1.x, r1.y, r2.x, r2.y};
                u32x4 p1 = {r1.z, r1.w, r2.z, r2.w};
                pa[u][0] = __builtin_bit_cast(bf16x8, p0);
                pa[u][1] = __builtin_bit_cast(bf16x8, p1);
            }

            // ---- rescale o/lacc (o-layout rows q' = 4g + r) ----
            float fro[4];
#pragma unroll
            for (int r = 0; r < 4; ++r) fro[r] = __shfl(fr, g * 4 + r);
#pragma unroll
            for (int cb = 0; cb < 4; ++cb)
#pragma unroll
                for (int r = 0; r < 4; ++r) o[u][cb][r] *= fro[r];
#pragma unroll
            for (int r = 0; r < 4; ++r) lacc[u][r] *= fro[r];

            lacc[u] = mfma16(pa[u][0], onesb, lacc[u]);
            lacc[u] = mfma16(pa[u][1], onesb, lacc[u]);
        }

        // ---- O += P V  (vf read once, feeds both subtiles) ----
#pragma unroll
        for (int cb = 0; cb < 4; ++cb) {
#pragma unroll
            for (int ks = 0; ks < 2; ++ks) {
                int d = cb * 16 + q16;
                int byt = (d * 128 + (ks * 32 + g * 8) * 2) ^ ((d & 7) << 4);
                bf16x8 vf = *(const bf16x8*)(VsB + byt);
                o[0][cb] = mfma16(pa[0][ks], vf, o[0][cb]);
                o[1][cb] = mfma16(pa[1][ks], vf, o[1][cb]);
            }
        }
        __syncthreads();
    }

    // ---- epilogue: O /= l, write bf16 [B,N,H*D] ----
    const int b = bh >> 4, h = bh & 15;
#pragma unroll
    for (int u = 0; u < 2; ++u) {
#pragma unroll
        for (int r = 0; r < 4; ++r) {
            float inv = 1.0f / lacc[u][r];
            int row = qt * 128 + wid * 32 + u * 16 + g * 4 + r;
#pragma unroll
            for (int cb = 0; cb < 4; ++cb) {
                int col = h * 64 + cb * 16 + q16;
                O[((size_t)(b * 2048 + row)) * 1024 + col] = f2bf(o[u][cb][r] * inv);
            }
        }
    }
}

// ---------------- launch ----------------
extern "C" void kernel_launch(void* const* d_in, const int* in_sizes, int n_in,
                              void* d_out, int out_size, void* d_ws, size_t ws_size,
                              hipStream_t stream) {
    const float* x  = (const float*)d_in[0];
    const float* Wq = (const float*)d_in[1];
    const float* Wk = (const float*)d_in[2];
    const float* Wv = (const float*)d_in[3];
    const float* Wo = (const float*)d_in[4];
    const float* bo = (const float*)d_in[5];
    float* out = (float*)d_out;

    if (ws_size < (size_t)72 * 1024 * 1024) return;
    ushort* ws  = (ushort*)d_ws;
    ushort* xb  = ws;
    ushort* wt  = xb + (size_t)8 * 1024 * 1024;
    ushort* qkv = wt + (size_t)4 * 1024 * 1024;
    ushort* ao  = xb;   // reuse xb after QKV GEMM consumed it

    cast_bf16_kernel<<<8192, 256, 0, stream>>>((const float4*)x, (ushort4*)xb,
                                               2 * 1024 * 1024);
    transpose_cast_kernel<<<dim3(32, 32, 4), dim3(32, 8), 0, stream>>>(Wq, Wk, Wv, Wo, wt);
    gemm128<0><<<dim3(64, 8, 3), 256, 0, stream>>>(xb, wt, qkv, nullptr, nullptr);
    attn_kernel<<<1024, 256, 0, stream>>>(
        qkv, qkv + (size_t)8 * 1024 * 1024, qkv + (size_t)16 * 1024 * 1024, ao);
    gemm128<1><<<dim3(64, 8, 1), 256, 0, stream>>>(ao, wt + (size_t)3 * 1024 * 1024,
                                                   nullptr, out, bo);
}

// Round 7
// 242.036 us; speedup vs baseline: 1.4165x; 1.0330x over previous
//
#include <hip/hip_runtime.h>
#include <hip/hip_bf16.h>

// Fused attention block: B=4, N=2048, C=1024, H=16, D=64
//   q/k/v = x@W{q,k,v}; attn = softmax(qk^T/8); out = (attn@v)@Wo + bo
// Strategy: cast to bf16, MFMA GEMMs (16x16x32), flash-style attention with
// swapped QK^T (S^T) -> in-lane softmax, 128 q-rows/block (2 subtiles/wave),
// XCD-chunked block swizzle. V staged in [64key][16d] panels via
// global_load_lds (exonerated by R5==R6 absmax identity), consumed via
// ds_read_b64_tr_b16 with SLOT addressing: the HW reads column
// (addr&127)>>3 of the 4x16 row-major subtile at addr&~127 (reconciles
// m156's layout formula with m162's uniform-addr behavior).

typedef __bf16 bf16x8 __attribute__((ext_vector_type(8)));   // 4 VGPRs, MFMA A/B frag
typedef __bf16 bf16x4 __attribute__((ext_vector_type(4)));   // 2 VGPRs, tr-read result
typedef float  f32x4  __attribute__((ext_vector_type(4)));   // MFMA C/D frag
typedef unsigned int u32x4 __attribute__((ext_vector_type(4)));

#define LSCALE 0.18033688f   // (1/8) * log2(e): softmax in exp2 domain

__device__ __forceinline__ f32x4 mfma16(bf16x8 a, bf16x8 b, f32x4 c) {
    return __builtin_amdgcn_mfma_f32_16x16x32_bf16(a, b, c, 0, 0, 0);
}

__device__ __forceinline__ unsigned short f2bf(float f) {
    unsigned u = __builtin_bit_cast(unsigned, f);
    u += 0x7fffu + ((u >> 16) & 1u);            // round-to-nearest-even
    return (unsigned short)(u >> 16);
}

__device__ __forceinline__ unsigned cvt_pk_bf16(float lo, float hi) {
    unsigned r;
    asm("v_cvt_pk_bf16_f32 %0, %1, %2" : "=v"(r) : "v"(lo), "v"(hi));
    return r;   // bits[15:0]=bf16(lo), bits[31:16]=bf16(hi)
}

// HW transpose read (slot semantics): returns the 4 bf16 of column
// (addr&127)>>3 of the 4x16 row-major bf16 subtile at addr&~127.
__device__ __forceinline__ bf16x4 trread(unsigned addr) {
    bf16x4 d;
    asm volatile("ds_read_b64_tr_b16 %0, %1" : "=v"(d) : "v"(addr));
    return d;   // caller MUST s_waitcnt lgkmcnt + sched_barrier before use
}

__device__ __forceinline__ void gload16(const ushort* g, ushort* l) {
    __builtin_amdgcn_global_load_lds(
        (const __attribute__((address_space(1))) void*)g,
        (__attribute__((address_space(3))) void*)l, 16, 0, 0);
}

// ---------------- cast fp32 -> bf16 (vectorized) ----------------
__global__ void cast_bf16_kernel(const float4* __restrict__ in,
                                 ushort4* __restrict__ out, int n4) {
    int i = blockIdx.x * blockDim.x + threadIdx.x;
    if (i < n4) {
        float4 f = in[i];
        ushort4 r;
        r.x = f2bf(f.x); r.y = f2bf(f.y); r.z = f2bf(f.z); r.w = f2bf(f.w);
        out[i] = r;
    }
}

// ---------------- transpose + cast weights: Wt[n][k] = bf16(W[k][n]) --------
__global__ void transpose_cast_kernel(const float* __restrict__ Wq,
                                      const float* __restrict__ Wk,
                                      const float* __restrict__ Wv,
                                      const float* __restrict__ Wo,
                                      ushort* __restrict__ out) {
    __shared__ float tile[32][33];
    const int z = blockIdx.z;
    const float* W = (z == 0) ? Wq : (z == 1) ? Wk : (z == 2) ? Wv : Wo;
    ushort* o = out + (size_t)z * 1024 * 1024;
    const int k0 = blockIdx.x * 32, n0 = blockIdx.y * 32;
    const int tx = threadIdx.x, ty = threadIdx.y;   // (32,8)
#pragma unroll
    for (int i = 0; i < 4; i++)
        tile[ty + 8 * i][tx] = W[(size_t)(k0 + ty + 8 * i) * 1024 + n0 + tx];
    __syncthreads();
#pragma unroll
    for (int i = 0; i < 4; i++)
        o[(size_t)(n0 + ty + 8 * i) * 1024 + k0 + tx] = f2bf(tile[tx][ty + 8 * i]);
}

// ---------------- 128x128 MFMA GEMM, K=1024, BK=32 (m97-style) ----------------
// MODE 0, z==0 (Q): output pre-scaled by LSCALE (folds softmax scale into Q).
template <int MODE>
__global__ __launch_bounds__(256) void gemm128(const ushort* __restrict__ A,
                                               const ushort* __restrict__ Bt,
                                               ushort* __restrict__ outB,
                                               float* __restrict__ outF,
                                               const float* __restrict__ bias) {
    __shared__ ushort As[128 * 32];
    __shared__ ushort Bs[128 * 32];
    const int tid = threadIdx.x;
    const int lane = tid & 63;
    const int wid = tid >> 6;
    const int wm = wid >> 1, wn = wid & 1;
    const int m0 = blockIdx.x * 128;
    const int n0 = blockIdx.y * 128;
    if (MODE == 0) Bt += (size_t)blockIdx.z * (1024 * 1024);

    f32x4 acc[4][4] = {};

    for (int k0 = 0; k0 < 1024; k0 += 32) {
#pragma unroll
        for (int it = 0; it < 2; ++it) {
            int e = (it * 256 + tid) * 8;
            int r = e >> 5, c = e & 31;
            gload16(&A[(size_t)(m0 + r) * 1024 + k0 + c], &As[e]);
            gload16(&Bt[(size_t)(n0 + r) * 1024 + k0 + c], &Bs[e]);
        }
        __syncthreads();

        bf16x8 a[4], b[4];
#pragma unroll
        for (int i = 0; i < 4; i++) {
            a[i] = *(const bf16x8*)&As[(wm * 64 + i * 16 + (lane & 15)) * 32 + (lane >> 4) * 8];
            b[i] = *(const bf16x8*)&Bs[(wn * 64 + i * 16 + (lane & 15)) * 32 + (lane >> 4) * 8];
        }
#pragma unroll
        for (int i = 0; i < 4; i++)
#pragma unroll
            for (int j = 0; j < 4; j++)
                acc[i][j] = mfma16(a[i], b[j], acc[i][j]);
        __syncthreads();
    }

    const float scl = (MODE == 0 && blockIdx.z == 0) ? LSCALE : 1.0f;
#pragma unroll
    for (int i = 0; i < 4; i++) {
        int row_b = m0 + wm * 64 + i * 16 + ((lane >> 4) * 4);
#pragma unroll
        for (int j = 0; j < 4; j++) {
            int col = n0 + wn * 64 + j * 16 + (lane & 15);
#pragma unroll
            for (int r = 0; r < 4; r++) {
                int row = row_b + r;
                float v = acc[i][j][r] * scl;
                if (MODE == 0) {
                    ushort* o = outB + (size_t)blockIdx.z * (8192ull * 1024);
                    int b = row >> 11, n = row & 2047, h = col >> 6, d = col & 63;
                    o[((((size_t)(b * 16 + h)) * 2048 + n) << 6) + d] = f2bf(v);
                } else {
                    outF[(size_t)row * 1024 + col] = v + bias[col];
                }
            }
        }
    }
}

// ---------------- flash attention ----------------
// grid 1024 (XCD-chunk swizzled -> (qt, bh)). block 256 = 4 waves.
// Block owns 128 q-rows; wave owns 32 (two 16-row subtiles u=0,1).
// Q,K,V in [B,H,N,D] bf16 (Q pre-scaled). O -> bf16 [B,N,H*D].
__global__ __launch_bounds__(256) void attn_kernel(const ushort* __restrict__ Q,
                                                   const ushort* __restrict__ K,
                                                   const ushort* __restrict__ V,
                                                   ushort* __restrict__ O) {
    __shared__ ushort Ks[64 * 64];        // [key][d], XOR-swizzled
    __shared__ ushort Vs[64 * 64];        // 4 panels [64 key][16 d] (panel=d>>4)
    __shared__ ushort Ps[4][2][1024];     // per-wave, per-subtile P exchange
    const int tid = threadIdx.x;
    const int lane = tid & 63;
    const int wid = tid >> 6;
    const int g = lane >> 4;          // 16-lane group
    const int q16 = lane & 15;
    const int bid = blockIdx.x;
    const int swz = (bid & 7) * 128 + (bid >> 3);   // XCD-chunked (1024 % 8 == 0)
    const int bh = swz >> 4;
    const int qt = swz & 15;
    const size_t base = (size_t)bh * (2048 * 64);

    // Q fragments (B-operand layout col=q16, k=g*8+j), two subtiles per wave
    const int qr0 = qt * 128 + wid * 32 + q16;
    bf16x8 qf[2][2];
#pragma unroll
    for (int u = 0; u < 2; ++u)
#pragma unroll
        for (int ks = 0; ks < 2; ++ks)
            qf[u][ks] = *(const bf16x8*)&Q[base + (size_t)(qr0 + u * 16) * 64 + ks * 32 + g * 8];

    bf16x8 onesb;
#pragma unroll
    for (int i = 0; i < 8; i++) onesb[i] = (__bf16)1.0f;

    f32x4 o[2][4] = {};
    f32x4 lacc[2] = {};
    float m_run[2] = {-1e30f, -1e30f};

    char* KsB = (char*)Ks;
    const unsigned vb = (unsigned)(size_t)&Vs[0];   // LDS byte addr

    for (int kt = 0; kt < 2048; kt += 64) {
        // ---- stage K (row-major, XOR-swizzled, explicit ds_write) ----
#pragma unroll
        for (int it = 0; it < 2; ++it) {
            int ci = it * 256 + tid;
            int key = ci >> 3, d0 = (ci & 7) * 8;
            uint4 kv = *(const uint4*)&K[base + (size_t)(kt + key) * 64 + d0];
            int byt = (key * 128 + d0 * 2) ^ ((key & 7) << 4);
            *(uint4*)(KsB + byt) = kv;
        }
        // ---- stage V panels via global_load_lds (linear dest, zero VALU) ----
        // chunk c: panel=c>>7, key=(c&127)>>1, d0=panel*16+(c&1)*8
#pragma unroll
        for (int it = 0; it < 2; ++it) {
            int c = it * 256 + tid;
            int key = (c & 127) >> 1;
            int d0 = (c >> 7) * 16 + (c & 1) * 8;
            gload16(&V[base + (size_t)(kt + key) * 64 + d0], &Vs[c * 8]);
        }
        __syncthreads();   // drains vmcnt (gload_lds) + lgkmcnt before use

        // ---- S^T = K Q^T : s[u][kb][r] = S[q=q16][key=kb*16+4g+r] ----
        f32x4 s[2][4] = {};
#pragma unroll
        for (int kb = 0; kb < 4; ++kb) {
#pragma unroll
            for (int ks = 0; ks < 2; ++ks) {
                int key = kb * 16 + q16;
                int d0 = ks * 32 + g * 8;
                int byt = (key * 128 + d0 * 2) ^ ((key & 7) << 4);
                bf16x8 kf = *(const bf16x8*)(KsB + byt);
                s[0][kb] = mfma16(kf, qf[0][ks], s[0][kb]);
                s[1][kb] = mfma16(kf, qf[1][ks], s[1][kb]);
            }
        }

        bf16x8 pa[2][2];
#pragma unroll
        for (int u = 0; u < 2; ++u) {
            // ---- in-lane online softmax (scale pre-folded into Q) ----
            float t[4][4];
#pragma unroll
            for (int kb = 0; kb < 4; ++kb)
#pragma unroll
                for (int r = 0; r < 4; ++r) t[kb][r] = s[u][kb][r];

            float mx = fmaxf(fmaxf(fmaxf(t[0][0], t[0][1]), fmaxf(t[0][2], t[0][3])),
                             fmaxf(fmaxf(t[1][0], t[1][1]), fmaxf(t[1][2], t[1][3])));
            mx = fmaxf(mx, fmaxf(fmaxf(fmaxf(t[2][0], t[2][1]), fmaxf(t[2][2], t[2][3])),
                                 fmaxf(fmaxf(t[3][0], t[3][1]), fmaxf(t[3][2], t[3][3]))));
            mx = fmaxf(mx, __shfl_xor(mx, 16));
            mx = fmaxf(mx, __shfl_xor(mx, 32));
            float mn = fmaxf(m_run[u], mx);
            float fr = __builtin_amdgcn_exp2f(m_run[u] - mn);
            m_run[u] = mn;

            unsigned w[4][2];
#pragma unroll
            for (int kb = 0; kb < 4; ++kb) {
                float p0 = __builtin_amdgcn_exp2f(t[kb][0] - mn);
                float p1 = __builtin_amdgcn_exp2f(t[kb][1] - mn);
                float p2 = __builtin_amdgcn_exp2f(t[kb][2] - mn);
                float p3 = __builtin_amdgcn_exp2f(t[kb][3] - mn);
                w[kb][0] = cvt_pk_bf16(p0, p1);
                w[kb][1] = cvt_pk_bf16(p2, p3);
            }

            // ---- P exchange: C-layout -> A-frag layout via wave-private LDS.
            char* PsB = (char*)Ps[wid][u];
            {
                u32x4 c0 = {w[0][0], w[0][1], w[2][0], w[2][1]};
                u32x4 c1 = {w[1][0], w[1][1], w[3][0], w[3][1]};
                *(u32x4*)(PsB + ((lane * 32 + 0)  ^ ((lane & 7) << 4))) = c0;
                *(u32x4*)(PsB + ((lane * 32 + 16) ^ ((lane & 7) << 4))) = c1;
            }
            asm volatile("" ::: "memory");
            __builtin_amdgcn_sched_barrier(0);
            int s1 = q16 + 32 * (g & 1);
            int ch = (g >> 1) * 16;
            u32x4 r1 = *(const u32x4*)(PsB + ((s1 * 32 + ch) ^ ((s1 & 7) << 4)));
            u32x4 r2 = *(const u32x4*)(PsB + (((s1 + 16) * 32 + ch) ^ (((s1 + 16) & 7) << 4)));
            asm volatile("" ::: "memory");
            {
                u32x4 p0 = {r1.x, r1.y, r2.x, r2.y};
                u32x4 p1 = {r1.z, r1.w, r2.z, r2.w};
                pa[u][0] = __builtin_bit_cast(bf16x8, p0);
                pa[u][1] = __builtin_bit_cast(bf16x8, p1);
            }

            // ---- rescale o/lacc (o-layout rows q' = 4g + r) ----
            float fro[4];
#pragma unroll
            for (int r = 0; r < 4; ++r) fro[r] = __shfl(fr, g * 4 + r);
#pragma unroll
            for (int cb = 0; cb < 4; ++cb)
#pragma unroll
                for (int r = 0; r < 4; ++r) o[u][cb][r] *= fro[r];
#pragma unroll
            for (int r = 0; r < 4; ++r) lacc[u][r] *= fro[r];

            lacc[u] = mfma16(pa[u][0], onesb, lacc[u]);
            lacc[u] = mfma16(pa[u][1], onesb, lacc[u]);
        }

        // ---- O += P V : V via HW transpose reads (slot addressing) ----
        // want vf[cb][ks][j] = V[key=ks*32+g*8+j][d=cb*16+q16]
        // block = panel cb + 4-key subtile (key0*32 bytes); slot = q16 -> +q16*8
        bf16x4 vlo[4][2], vhi[4][2];
#pragma unroll
        for (int cb = 0; cb < 4; ++cb)
#pragma unroll
            for (int ks = 0; ks < 2; ++ks) {
                unsigned a = vb + cb * 2048 + (ks * 32 + g * 8) * 32 + q16 * 8;
                vlo[cb][ks] = trread(a);
                vhi[cb][ks] = trread(a + 128);
            }
        asm volatile("s_waitcnt lgkmcnt(0)" ::: "memory");
        __builtin_amdgcn_sched_barrier(0);
#pragma unroll
        for (int cb = 0; cb < 4; ++cb)
#pragma unroll
            for (int ks = 0; ks < 2; ++ks) {
                bf16x8 vf = __builtin_shufflevector(vlo[cb][ks], vhi[cb][ks],
                                                    0, 1, 2, 3, 4, 5, 6, 7);
                o[0][cb] = mfma16(pa[0][ks], vf, o[0][cb]);
                o[1][cb] = mfma16(pa[1][ks], vf, o[1][cb]);
            }
        __syncthreads();
    }

    // ---- epilogue: O /= l, write bf16 [B,N,H*D] ----
    const int b = bh >> 4, h = bh & 15;
#pragma unroll
    for (int u = 0; u < 2; ++u) {
#pragma unroll
        for (int r = 0; r < 4; ++r) {
            float inv = 1.0f / lacc[u][r];
            int row = qt * 128 + wid * 32 + u * 16 + g * 4 + r;
#pragma unroll
            for (int cb = 0; cb < 4; ++cb) {
                int col = h * 64 + cb * 16 + q16;
                O[((size_t)(b * 2048 + row)) * 1024 + col] = f2bf(o[u][cb][r] * inv);
            }
        }
    }
}

// ---------------- launch ----------------
extern "C" void kernel_launch(void* const* d_in, const int* in_sizes, int n_in,
                              void* d_out, int out_size, void* d_ws, size_t ws_size,
                              hipStream_t stream) {
    const float* x  = (const float*)d_in[0];
    const float* Wq = (const float*)d_in[1];
    const float* Wk = (const float*)d_in[2];
    const float* Wv = (const float*)d_in[3];
    const float* Wo = (const float*)d_in[4];
    const float* bo = (const float*)d_in[5];
    float* out = (float*)d_out;

    if (ws_size < (size_t)72 * 1024 * 1024) return;
    ushort* ws  = (ushort*)d_ws;
    ushort* xb  = ws;
    ushort* wt  = xb + (size_t)8 * 1024 * 1024;
    ushort* qkv = wt + (size_t)4 * 1024 * 1024;
    ushort* ao  = xb;   // reuse xb after QKV GEMM consumed it

    cast_bf16_kernel<<<8192, 256, 0, stream>>>((const float4*)x, (ushort4*)xb,
                                               2 * 1024 * 1024);
    transpose_cast_kernel<<<dim3(32, 32, 4), dim3(32, 8), 0, stream>>>(Wq, Wk, Wv, Wo, wt);
    gemm128<0><<<dim3(64, 8, 3), 256, 0, stream>>>(xb, wt, qkv, nullptr, nullptr);
    attn_kernel<<<1024, 256, 0, stream>>>(
        qkv, qkv + (size_t)8 * 1024 * 1024, qkv + (size_t)16 * 1024 * 1024, ao);
    gemm128<1><<<dim3(64, 8, 1), 256, 0, stream>>>(ao, wt + (size_t)3 * 1024 * 1024,
                                                   nullptr, out, bo);
}

// Round 8
// 236.962 us; speedup vs baseline: 1.4468x; 1.0214x over previous
//
#include <hip/hip_runtime.h>
#include <hip/hip_bf16.h>

// Fused attention block: B=4, N=2048, C=1024, H=16, D=64
//   q/k/v = x@W{q,k,v}; attn = softmax(qk^T/8); out = (attn@v)@Wo + bo
// Strategy: cast to bf16, MFMA GEMMs (16x16x32), flash-style attention with
// swapped QK^T (S^T) -> in-lane softmax, 128 q-rows/block (2 subtiles/wave),
// XCD-chunked block swizzle, ds_read_b64_tr_b16 PV (slot addressing), and a
// 2-phase double-buffered K/V pipeline: next-tile V via global_load_lds DMA +
// K via global->reg issued BEFORE compute, K ds_write after, ONE barrier/tile.

typedef __bf16 bf16x8 __attribute__((ext_vector_type(8)));   // 4 VGPRs, MFMA A/B frag
typedef __bf16 bf16x4 __attribute__((ext_vector_type(4)));   // 2 VGPRs, tr-read result
typedef float  f32x4  __attribute__((ext_vector_type(4)));   // MFMA C/D frag
typedef unsigned int u32x4 __attribute__((ext_vector_type(4)));

#define LSCALE 0.18033688f   // (1/8) * log2(e): softmax in exp2 domain

__device__ __forceinline__ f32x4 mfma16(bf16x8 a, bf16x8 b, f32x4 c) {
    return __builtin_amdgcn_mfma_f32_16x16x32_bf16(a, b, c, 0, 0, 0);
}

__device__ __forceinline__ unsigned short f2bf(float f) {
    unsigned u = __builtin_bit_cast(unsigned, f);
    u += 0x7fffu + ((u >> 16) & 1u);            // round-to-nearest-even
    return (unsigned short)(u >> 16);
}

__device__ __forceinline__ unsigned cvt_pk_bf16(float lo, float hi) {
    unsigned r;
    asm("v_cvt_pk_bf16_f32 %0, %1, %2" : "=v"(r) : "v"(lo), "v"(hi));
    return r;   // bits[15:0]=bf16(lo), bits[31:16]=bf16(hi)
}

// HW transpose read (slot semantics, verified R7): returns the 4 bf16 of
// column (addr&127)>>3 of the 4x16 row-major bf16 subtile at addr&~127.
__device__ __forceinline__ bf16x4 trread(unsigned addr) {
    bf16x4 d;
    asm volatile("ds_read_b64_tr_b16 %0, %1" : "=v"(d) : "v"(addr));
    return d;   // caller MUST s_waitcnt lgkmcnt + sched_barrier before use
}

__device__ __forceinline__ void gload16(const ushort* g, ushort* l) {
    __builtin_amdgcn_global_load_lds(
        (const __attribute__((address_space(1))) void*)g,
        (__attribute__((address_space(3))) void*)l, 16, 0, 0);
}

// ---------------- cast fp32 -> bf16 (vectorized) ----------------
__global__ void cast_bf16_kernel(const float4* __restrict__ in,
                                 ushort4* __restrict__ out, int n4) {
    int i = blockIdx.x * blockDim.x + threadIdx.x;
    if (i < n4) {
        float4 f = in[i];
        ushort4 r;
        r.x = f2bf(f.x); r.y = f2bf(f.y); r.z = f2bf(f.z); r.w = f2bf(f.w);
        out[i] = r;
    }
}

// ---------------- transpose + cast weights: Wt[n][k] = bf16(W[k][n]) --------
__global__ void transpose_cast_kernel(const float* __restrict__ Wq,
                                      const float* __restrict__ Wk,
                                      const float* __restrict__ Wv,
                                      const float* __restrict__ Wo,
                                      ushort* __restrict__ out) {
    __shared__ float tile[32][33];
    const int z = blockIdx.z;
    const float* W = (z == 0) ? Wq : (z == 1) ? Wk : (z == 2) ? Wv : Wo;
    ushort* o = out + (size_t)z * 1024 * 1024;
    const int k0 = blockIdx.x * 32, n0 = blockIdx.y * 32;
    const int tx = threadIdx.x, ty = threadIdx.y;   // (32,8)
#pragma unroll
    for (int i = 0; i < 4; i++)
        tile[ty + 8 * i][tx] = W[(size_t)(k0 + ty + 8 * i) * 1024 + n0 + tx];
    __syncthreads();
#pragma unroll
    for (int i = 0; i < 4; i++)
        o[(size_t)(n0 + ty + 8 * i) * 1024 + k0 + tx] = f2bf(tile[tx][ty + 8 * i]);
}

// ---------------- 128x128 MFMA GEMM, K=1024, BK=32 (m97-style) ----------------
// MODE 0, z==0 (Q): output pre-scaled by LSCALE (folds softmax scale into Q).
template <int MODE>
__global__ __launch_bounds__(256) void gemm128(const ushort* __restrict__ A,
                                               const ushort* __restrict__ Bt,
                                               ushort* __restrict__ outB,
                                               float* __restrict__ outF,
                                               const float* __restrict__ bias) {
    __shared__ ushort As[128 * 32];
    __shared__ ushort Bs[128 * 32];
    const int tid = threadIdx.x;
    const int lane = tid & 63;
    const int wid = tid >> 6;
    const int wm = wid >> 1, wn = wid & 1;
    const int m0 = blockIdx.x * 128;
    const int n0 = blockIdx.y * 128;
    if (MODE == 0) Bt += (size_t)blockIdx.z * (1024 * 1024);

    f32x4 acc[4][4] = {};

    for (int k0 = 0; k0 < 1024; k0 += 32) {
#pragma unroll
        for (int it = 0; it < 2; ++it) {
            int e = (it * 256 + tid) * 8;
            int r = e >> 5, c = e & 31;
            gload16(&A[(size_t)(m0 + r) * 1024 + k0 + c], &As[e]);
            gload16(&Bt[(size_t)(n0 + r) * 1024 + k0 + c], &Bs[e]);
        }
        __syncthreads();

        bf16x8 a[4], b[4];
#pragma unroll
        for (int i = 0; i < 4; i++) {
            a[i] = *(const bf16x8*)&As[(wm * 64 + i * 16 + (lane & 15)) * 32 + (lane >> 4) * 8];
            b[i] = *(const bf16x8*)&Bs[(wn * 64 + i * 16 + (lane & 15)) * 32 + (lane >> 4) * 8];
        }
#pragma unroll
        for (int i = 0; i < 4; i++)
#pragma unroll
            for (int j = 0; j < 4; j++)
                acc[i][j] = mfma16(a[i], b[j], acc[i][j]);
        __syncthreads();
    }

    const float scl = (MODE == 0 && blockIdx.z == 0) ? LSCALE : 1.0f;
#pragma unroll
    for (int i = 0; i < 4; i++) {
        int row_b = m0 + wm * 64 + i * 16 + ((lane >> 4) * 4);
#pragma unroll
        for (int j = 0; j < 4; j++) {
            int col = n0 + wn * 64 + j * 16 + (lane & 15);
#pragma unroll
            for (int r = 0; r < 4; r++) {
                int row = row_b + r;
                float v = acc[i][j][r] * scl;
                if (MODE == 0) {
                    ushort* o = outB + (size_t)blockIdx.z * (8192ull * 1024);
                    int b = row >> 11, n = row & 2047, h = col >> 6, d = col & 63;
                    o[((((size_t)(b * 16 + h)) * 2048 + n) << 6) + d] = f2bf(v);
                } else {
                    outF[(size_t)row * 1024 + col] = v + bias[col];
                }
            }
        }
    }
}

// ---------------- flash attention ----------------
// grid 1024 (XCD-chunk swizzled -> (qt, bh)). block 256 = 4 waves.
// Block owns 128 q-rows; wave owns 32 (two 16-row subtiles u=0,1).
// Q,K,V in [B,H,N,D] bf16 (Q pre-scaled). O -> bf16 [B,N,H*D].
__global__ __launch_bounds__(256) void attn_kernel(const ushort* __restrict__ Q,
                                                   const ushort* __restrict__ K,
                                                   const ushort* __restrict__ V,
                                                   ushort* __restrict__ O) {
    __shared__ ushort Ks[2][64 * 64];     // dbuf, [key][d] XOR-swizzled
    __shared__ ushort Vs[2][64 * 64];     // dbuf, 4 panels [64 key][16 d]
    __shared__ ushort Ps[4][2][1024];     // per-wave, per-subtile P exchange
    const int tid = threadIdx.x;
    const int lane = tid & 63;
    const int wid = tid >> 6;
    const int g = lane >> 4;          // 16-lane group
    const int q16 = lane & 15;
    const int bid = blockIdx.x;
    const int swz = (bid & 7) * 128 + (bid >> 3);   // XCD-chunked (1024 % 8 == 0)
    const int bh = swz >> 4;
    const int qt = swz & 15;
    const size_t base = (size_t)bh * (2048 * 64);

    // Q fragments (B-operand layout col=q16, k=g*8+j), two subtiles per wave
    const int qr0 = qt * 128 + wid * 32 + q16;
    bf16x8 qf[2][2];
#pragma unroll
    for (int u = 0; u < 2; ++u)
#pragma unroll
        for (int ks = 0; ks < 2; ++ks)
            qf[u][ks] = *(const bf16x8*)&Q[base + (size_t)(qr0 + u * 16) * 64 + ks * 32 + g * 8];

    bf16x8 onesb;
#pragma unroll
    for (int i = 0; i < 8; i++) onesb[i] = (__bf16)1.0f;

    f32x4 o[2][4] = {};
    f32x4 lacc[2] = {};
    float m_run[2] = {-1e30f, -1e30f};

    // per-thread staging chunk coordinates (constant across tiles)
    const int kci0 = tid, kci1 = 256 + tid;                 // K chunks
    const int kkey0 = kci0 >> 3, kd0 = (kci0 & 7) * 8;
    const int kkey1 = kci1 >> 3, kd1 = (kci1 & 7) * 8;
    const int kbyt0 = (kkey0 * 128 + kd0 * 2) ^ ((kkey0 & 7) << 4);
    const int kbyt1 = (kkey1 * 128 + kd1 * 2) ^ ((kkey1 & 7) << 4);
    const int vkey0 = (kci0 & 127) >> 1, vd0 = (kci0 >> 7) * 16 + (kci0 & 1) * 8;
    const int vkey1 = (kci1 & 127) >> 1, vd1 = (kci1 >> 7) * 16 + (kci1 & 1) * 8;

    char* const KsB0 = (char*)&Ks[0][0];
    ushort* const Vs0 = &Vs[0][0];
    const unsigned vb0 = (unsigned)(size_t)&Vs[0][0];

    // ---- prologue: stage tile 0 into buffer 0 ----
    {
        uint4 k0 = *(const uint4*)&K[base + (size_t)kkey0 * 64 + kd0];
        uint4 k1 = *(const uint4*)&K[base + (size_t)kkey1 * 64 + kd1];
        gload16(&V[base + (size_t)vkey0 * 64 + vd0], &Vs0[kci0 * 8]);
        gload16(&V[base + (size_t)vkey1 * 64 + vd1], &Vs0[kci1 * 8]);
        *(uint4*)(KsB0 + kbyt0) = k0;
        *(uint4*)(KsB0 + kbyt1) = k1;
    }
    __syncthreads();   // drains vmcnt(0)+lgkmcnt(0): tile 0 resident

    int cur = 0;
    for (int kt = 0; kt < 2048; kt += 64) {
        const int nxt = cur ^ 1;
        const bool more = (kt + 64) < 2048;
        char* const KsBc = KsB0 + cur * 8192;        // ptr math, not runtime idx
        const unsigned vbc = vb0 + cur * 8192;

        // ---- issue next tile's staging EARLY (hides HBM under compute) ----
        uint4 kn0, kn1;
        if (more) {
            const size_t nb = base + (size_t)(kt + 64) * 64;
            gload16(&V[nb + (size_t)vkey0 * 64 + vd0], &Vs0[nxt * 4096 + kci0 * 8]);
            gload16(&V[nb + (size_t)vkey1 * 64 + vd1], &Vs0[nxt * 4096 + kci1 * 8]);
            kn0 = *(const uint4*)&K[nb + (size_t)kkey0 * 64 + kd0];
            kn1 = *(const uint4*)&K[nb + (size_t)kkey1 * 64 + kd1];
        }

        // ---- S^T = K Q^T : s[u][kb][r] = S[q=q16][key=kb*16+4g+r] ----
        f32x4 s[2][4] = {};
#pragma unroll
        for (int kb = 0; kb < 4; ++kb) {
#pragma unroll
            for (int ks = 0; ks < 2; ++ks) {
                int key = kb * 16 + q16;
                int d0 = ks * 32 + g * 8;
                int byt = (key * 128 + d0 * 2) ^ ((key & 7) << 4);
                bf16x8 kf = *(const bf16x8*)(KsBc + byt);
                s[0][kb] = mfma16(kf, qf[0][ks], s[0][kb]);
                s[1][kb] = mfma16(kf, qf[1][ks], s[1][kb]);
            }
        }

        bf16x8 pa[2][2];
#pragma unroll
        for (int u = 0; u < 2; ++u) {
            // ---- in-lane online softmax (scale pre-folded into Q) ----
            float t[4][4];
#pragma unroll
            for (int kb = 0; kb < 4; ++kb)
#pragma unroll
                for (int r = 0; r < 4; ++r) t[kb][r] = s[u][kb][r];

            float mx = fmaxf(fmaxf(fmaxf(t[0][0], t[0][1]), fmaxf(t[0][2], t[0][3])),
                             fmaxf(fmaxf(t[1][0], t[1][1]), fmaxf(t[1][2], t[1][3])));
            mx = fmaxf(mx, fmaxf(fmaxf(fmaxf(t[2][0], t[2][1]), fmaxf(t[2][2], t[2][3])),
                                 fmaxf(fmaxf(t[3][0], t[3][1]), fmaxf(t[3][2], t[3][3]))));
            mx = fmaxf(mx, __shfl_xor(mx, 16));
            mx = fmaxf(mx, __shfl_xor(mx, 32));
            float mn = fmaxf(m_run[u], mx);
            float fr = __builtin_amdgcn_exp2f(m_run[u] - mn);
            m_run[u] = mn;

            unsigned w[4][2];
#pragma unroll
            for (int kb = 0; kb < 4; ++kb) {
                float p0 = __builtin_amdgcn_exp2f(t[kb][0] - mn);
                float p1 = __builtin_amdgcn_exp2f(t[kb][1] - mn);
                float p2 = __builtin_amdgcn_exp2f(t[kb][2] - mn);
                float p3 = __builtin_amdgcn_exp2f(t[kb][3] - mn);
                w[kb][0] = cvt_pk_bf16(p0, p1);
                w[kb][1] = cvt_pk_bf16(p2, p3);
            }

            // ---- P exchange: C-layout -> A-frag layout via wave-private LDS.
            char* PsB = (char*)Ps[wid][u];
            {
                u32x4 c0 = {w[0][0], w[0][1], w[2][0], w[2][1]};
                u32x4 c1 = {w[1][0], w[1][1], w[3][0], w[3][1]};
                *(u32x4*)(PsB + ((lane * 32 + 0)  ^ ((lane & 7) << 4))) = c0;
                *(u32x4*)(PsB + ((lane * 32 + 16) ^ ((lane & 7) << 4))) = c1;
            }
            asm volatile("" ::: "memory");
            __builtin_amdgcn_sched_barrier(0);
            int s1 = q16 + 32 * (g & 1);
            int ch = (g >> 1) * 16;
            u32x4 r1 = *(const u32x4*)(PsB + ((s1 * 32 + ch) ^ ((s1 & 7) << 4)));
            u32x4 r2 = *(const u32x4*)(PsB + (((s1 + 16) * 32 + ch) ^ (((s1 + 16) & 7) << 4)));
            asm volatile("" ::: "memory");
            {
                u32x4 p0 = {r1.x, r1.y, r2.x, r2.y};
                u32x4 p1 = {r1.z, r1.w, r2.z, r2.w};
                pa[u][0] = __builtin_bit_cast(bf16x8, p0);
                pa[u][1] = __builtin_bit_cast(bf16x8, p1);
            }

            // ---- rescale o/lacc (o-layout rows q' = 4g + r) ----
            float fro[4];
#pragma unroll
            for (int r = 0; r < 4; ++r) fro[r] = __shfl(fr, g * 4 + r);
#pragma unroll
            for (int cb = 0; cb < 4; ++cb)
#pragma unroll
                for (int r = 0; r < 4; ++r) o[u][cb][r] *= fro[r];
#pragma unroll
            for (int r = 0; r < 4; ++r) lacc[u][r] *= fro[r];

            lacc[u] = mfma16(pa[u][0], onesb, lacc[u]);
            lacc[u] = mfma16(pa[u][1], onesb, lacc[u]);
        }

        // ---- O += P V : V via HW transpose reads (slot addressing) ----
        bf16x4 vlo[4][2], vhi[4][2];
#pragma unroll
        for (int cb = 0; cb < 4; ++cb)
#pragma unroll
            for (int ks = 0; ks < 2; ++ks) {
                unsigned a = vbc + cb * 2048 + (ks * 32 + g * 8) * 32 + q16 * 8;
                vlo[cb][ks] = trread(a);
                vhi[cb][ks] = trread(a + 128);
            }
        asm volatile("s_waitcnt lgkmcnt(0)" ::: "memory");
        __builtin_amdgcn_sched_barrier(0);
#pragma unroll
        for (int cb = 0; cb < 4; ++cb)
#pragma unroll
            for (int ks = 0; ks < 2; ++ks) {
                bf16x8 vf = __builtin_shufflevector(vlo[cb][ks], vhi[cb][ks],
                                                    0, 1, 2, 3, 4, 5, 6, 7);
                o[0][cb] = mfma16(pa[0][ks], vf, o[0][cb]);
                o[1][cb] = mfma16(pa[1][ks], vf, o[1][cb]);
            }

        // ---- write next tile's K regs into buf nxt, single barrier ----
        if (more) {
            char* const KsBn = KsB0 + nxt * 8192;
            *(uint4*)(KsBn + kbyt0) = kn0;
            *(uint4*)(KsBn + kbyt1) = kn1;
        }
        __syncthreads();   // drains vmcnt (V DMA) + lgkmcnt (K writes)
        cur = nxt;
    }

    // ---- epilogue: O /= l, write bf16 [B,N,H*D] ----
    const int b = bh >> 4, h = bh & 15;
#pragma unroll
    for (int u = 0; u < 2; ++u) {
#pragma unroll
        for (int r = 0; r < 4; ++r) {
            float inv = 1.0f / lacc[u][r];
            int row = qt * 128 + wid * 32 + u * 16 + g * 4 + r;
#pragma unroll
            for (int cb = 0; cb < 4; ++cb) {
                int col = h * 64 + cb * 16 + q16;
                O[((size_t)(b * 2048 + row)) * 1024 + col] = f2bf(o[u][cb][r] * inv);
            }
        }
    }
}

// ---------------- launch ----------------
extern "C" void kernel_launch(void* const* d_in, const int* in_sizes, int n_in,
                              void* d_out, int out_size, void* d_ws, size_t ws_size,
                              hipStream_t stream) {
    const float* x  = (const float*)d_in[0];
    const float* Wq = (const float*)d_in[1];
    const float* Wk = (const float*)d_in[2];
    const float* Wv = (const float*)d_in[3];
    const float* Wo = (const float*)d_in[4];
    const float* bo = (const float*)d_in[5];
    float* out = (float*)d_out;

    if (ws_size < (size_t)72 * 1024 * 1024) return;
    ushort* ws  = (ushort*)d_ws;
    ushort* xb  = ws;
    ushort* wt  = xb + (size_t)8 * 1024 * 1024;
    ushort* qkv = wt + (size_t)4 * 1024 * 1024;
    ushort* ao  = xb;   // reuse xb after QKV GEMM consumed it

    cast_bf16_kernel<<<8192, 256, 0, stream>>>((const float4*)x, (ushort4*)xb,
                                               2 * 1024 * 1024);
    transpose_cast_kernel<<<dim3(32, 32, 4), dim3(32, 8), 0, stream>>>(Wq, Wk, Wv, Wo, wt);
    gemm128<0><<<dim3(64, 8, 3), 256, 0, stream>>>(xb, wt, qkv, nullptr, nullptr);
    attn_kernel<<<1024, 256, 0, stream>>>(
        qkv, qkv + (size_t)8 * 1024 * 1024, qkv + (size_t)16 * 1024 * 1024, ao);
    gemm128<1><<<dim3(64, 8, 1), 256, 0, stream>>>(ao, wt + (size_t)3 * 1024 * 1024,
                                                   nullptr, out, bo);
}

// Round 9
// 218.361 us; speedup vs baseline: 1.5701x; 1.0852x over previous
//
#include <hip/hip_runtime.h>
#include <hip/hip_bf16.h>

// Fused attention block: B=4, N=2048, C=1024, H=16, D=64
//   q/k/v = x@W{q,k,v}; attn = softmax(qk^T/8); out = (attn@v)@Wo + bo
// Strategy: cast to bf16, MFMA GEMMs (16x16x32), flash-style attention with
// swapped QK^T (S^T) -> in-lane softmax, 128 q-rows/block (2 subtiles/wave),
// XCD-chunked block swizzle, ds_read_b64_tr_b16 PV (slot addressing),
// 2-phase double-buffered K/V pipeline (one barrier/tile), 40KB LDS
// (4 blocks/CU), defer-rescale (T13, log2-THR=8), max3-shaped max tree.

typedef __bf16 bf16x8 __attribute__((ext_vector_type(8)));   // 4 VGPRs, MFMA A/B frag
typedef __bf16 bf16x4 __attribute__((ext_vector_type(4)));   // 2 VGPRs, tr-read result
typedef float  f32x4  __attribute__((ext_vector_type(4)));   // MFMA C/D frag
typedef unsigned int u32x4 __attribute__((ext_vector_type(4)));

#define LSCALE 0.18033688f   // (1/8) * log2(e): softmax in exp2 domain
#define DEFER_THR 8.0f       // skip rescale while max grows < 8 (log2): P <= 256

__device__ __forceinline__ f32x4 mfma16(bf16x8 a, bf16x8 b, f32x4 c) {
    return __builtin_amdgcn_mfma_f32_16x16x32_bf16(a, b, c, 0, 0, 0);
}

__device__ __forceinline__ unsigned short f2bf(float f) {
    unsigned u = __builtin_bit_cast(unsigned, f);
    u += 0x7fffu + ((u >> 16) & 1u);            // round-to-nearest-even
    return (unsigned short)(u >> 16);
}

__device__ __forceinline__ unsigned cvt_pk_bf16(float lo, float hi) {
    unsigned r;
    asm("v_cvt_pk_bf16_f32 %0, %1, %2" : "=v"(r) : "v"(lo), "v"(hi));
    return r;   // bits[15:0]=bf16(lo), bits[31:16]=bf16(hi)
}

// HW transpose read (slot semantics, verified R7): returns the 4 bf16 of
// column (addr&127)>>3 of the 4x16 row-major bf16 subtile at addr&~127.
__device__ __forceinline__ bf16x4 trread(unsigned addr) {
    bf16x4 d;
    asm volatile("ds_read_b64_tr_b16 %0, %1" : "=v"(d) : "v"(addr));
    return d;   // caller MUST s_waitcnt lgkmcnt + sched_barrier before use
}

__device__ __forceinline__ void gload16(const ushort* g, ushort* l) {
    __builtin_amdgcn_global_load_lds(
        (const __attribute__((address_space(1))) void*)g,
        (__attribute__((address_space(3))) void*)l, 16, 0, 0);
}

// ---------------- cast fp32 -> bf16 (vectorized) ----------------
__global__ void cast_bf16_kernel(const float4* __restrict__ in,
                                 ushort4* __restrict__ out, int n4) {
    int i = blockIdx.x * blockDim.x + threadIdx.x;
    if (i < n4) {
        float4 f = in[i];
        ushort4 r;
        r.x = f2bf(f.x); r.y = f2bf(f.y); r.z = f2bf(f.z); r.w = f2bf(f.w);
        out[i] = r;
    }
}

// ---------------- transpose + cast weights: Wt[n][k] = bf16(W[k][n]) --------
__global__ void transpose_cast_kernel(const float* __restrict__ Wq,
                                      const float* __restrict__ Wk,
                                      const float* __restrict__ Wv,
                                      const float* __restrict__ Wo,
                                      ushort* __restrict__ out) {
    __shared__ float tile[32][33];
    const int z = blockIdx.z;
    const float* W = (z == 0) ? Wq : (z == 1) ? Wk : (z == 2) ? Wv : Wo;
    ushort* o = out + (size_t)z * 1024 * 1024;
    const int k0 = blockIdx.x * 32, n0 = blockIdx.y * 32;
    const int tx = threadIdx.x, ty = threadIdx.y;   // (32,8)
#pragma unroll
    for (int i = 0; i < 4; i++)
        tile[ty + 8 * i][tx] = W[(size_t)(k0 + ty + 8 * i) * 1024 + n0 + tx];
    __syncthreads();
#pragma unroll
    for (int i = 0; i < 4; i++)
        o[(size_t)(n0 + ty + 8 * i) * 1024 + k0 + tx] = f2bf(tile[tx][ty + 8 * i]);
}

// ---------------- 128x128 MFMA GEMM, K=1024, BK=32 (m97-style) ----------------
// MODE 0, z==0 (Q): output pre-scaled by LSCALE (folds softmax scale into Q).
template <int MODE>
__global__ __launch_bounds__(256) void gemm128(const ushort* __restrict__ A,
                                               const ushort* __restrict__ Bt,
                                               ushort* __restrict__ outB,
                                               float* __restrict__ outF,
                                               const float* __restrict__ bias) {
    __shared__ ushort As[128 * 32];
    __shared__ ushort Bs[128 * 32];
    const int tid = threadIdx.x;
    const int lane = tid & 63;
    const int wid = tid >> 6;
    const int wm = wid >> 1, wn = wid & 1;
    const int m0 = blockIdx.x * 128;
    const int n0 = blockIdx.y * 128;
    if (MODE == 0) Bt += (size_t)blockIdx.z * (1024 * 1024);

    f32x4 acc[4][4] = {};

    for (int k0 = 0; k0 < 1024; k0 += 32) {
#pragma unroll
        for (int it = 0; it < 2; ++it) {
            int e = (it * 256 + tid) * 8;
            int r = e >> 5, c = e & 31;
            gload16(&A[(size_t)(m0 + r) * 1024 + k0 + c], &As[e]);
            gload16(&Bt[(size_t)(n0 + r) * 1024 + k0 + c], &Bs[e]);
        }
        __syncthreads();

        bf16x8 a[4], b[4];
#pragma unroll
        for (int i = 0; i < 4; i++) {
            a[i] = *(const bf16x8*)&As[(wm * 64 + i * 16 + (lane & 15)) * 32 + (lane >> 4) * 8];
            b[i] = *(const bf16x8*)&Bs[(wn * 64 + i * 16 + (lane & 15)) * 32 + (lane >> 4) * 8];
        }
#pragma unroll
        for (int i = 0; i < 4; i++)
#pragma unroll
            for (int j = 0; j < 4; j++)
                acc[i][j] = mfma16(a[i], b[j], acc[i][j]);
        __syncthreads();
    }

    const float scl = (MODE == 0 && blockIdx.z == 0) ? LSCALE : 1.0f;
#pragma unroll
    for (int i = 0; i < 4; i++) {
        int row_b = m0 + wm * 64 + i * 16 + ((lane >> 4) * 4);
#pragma unroll
        for (int j = 0; j < 4; j++) {
            int col = n0 + wn * 64 + j * 16 + (lane & 15);
#pragma unroll
            for (int r = 0; r < 4; r++) {
                int row = row_b + r;
                float v = acc[i][j][r] * scl;
                if (MODE == 0) {
                    ushort* o = outB + (size_t)blockIdx.z * (8192ull * 1024);
                    int b = row >> 11, n = row & 2047, h = col >> 6, d = col & 63;
                    o[((((size_t)(b * 16 + h)) * 2048 + n) << 6) + d] = f2bf(v);
                } else {
                    outF[(size_t)row * 1024 + col] = v + bias[col];
                }
            }
        }
    }
}

// ---------------- flash attention ----------------
// grid 1024 (XCD-chunk swizzled -> (qt, bh)). block 256 = 4 waves.
// Block owns 128 q-rows; wave owns 32 (two 16-row subtiles u=0,1).
// Q,K,V in [B,H,N,D] bf16 (Q pre-scaled). O -> bf16 [B,N,H*D].
__global__ __launch_bounds__(256) void attn_kernel(const ushort* __restrict__ Q,
                                                   const ushort* __restrict__ K,
                                                   const ushort* __restrict__ V,
                                                   ushort* __restrict__ O) {
    __shared__ ushort Ks[2][64 * 64];     // dbuf, [key][d] XOR-swizzled (16KB)
    __shared__ ushort Vs[2][64 * 64];     // dbuf, 4 panels [64 key][16 d] (16KB)
    __shared__ ushort Ps[4][1024];        // per-wave P exchange, reused u=0,1 (8KB)
    const int tid = threadIdx.x;
    const int lane = tid & 63;
    const int wid = tid >> 6;
    const int g = lane >> 4;          // 16-lane group
    const int q16 = lane & 15;
    const int bid = blockIdx.x;
    const int swz = (bid & 7) * 128 + (bid >> 3);   // XCD-chunked (1024 % 8 == 0)
    const int bh = swz >> 4;
    const int qt = swz & 15;
    const size_t base = (size_t)bh * (2048 * 64);

    // Q fragments (B-operand layout col=q16, k=g*8+j), two subtiles per wave
    const int qr0 = qt * 128 + wid * 32 + q16;
    bf16x8 qf[2][2];
#pragma unroll
    for (int u = 0; u < 2; ++u)
#pragma unroll
        for (int ks = 0; ks < 2; ++ks)
            qf[u][ks] = *(const bf16x8*)&Q[base + (size_t)(qr0 + u * 16) * 64 + ks * 32 + g * 8];

    bf16x8 onesb;
#pragma unroll
    for (int i = 0; i < 8; i++) onesb[i] = (__bf16)1.0f;

    f32x4 o[2][4] = {};
    f32x4 lacc[2] = {};
    float m_run[2] = {-1e30f, -1e30f};

    // per-thread staging chunk coordinates (constant across tiles)
    const int kci0 = tid, kci1 = 256 + tid;                 // K chunks
    const int kkey0 = kci0 >> 3, kd0 = (kci0 & 7) * 8;
    const int kkey1 = kci1 >> 3, kd1 = (kci1 & 7) * 8;
    const int kbyt0 = (kkey0 * 128 + kd0 * 2) ^ ((kkey0 & 7) << 4);
    const int kbyt1 = (kkey1 * 128 + kd1 * 2) ^ ((kkey1 & 7) << 4);
    const int vkey0 = (kci0 & 127) >> 1, vd0 = (kci0 >> 7) * 16 + (kci0 & 1) * 8;
    const int vkey1 = (kci1 & 127) >> 1, vd1 = (kci1 >> 7) * 16 + (kci1 & 1) * 8;

    char* const KsB0 = (char*)&Ks[0][0];
    ushort* const Vs0 = &Vs[0][0];
    const unsigned vb0 = (unsigned)(size_t)&Vs[0][0];

    // ---- prologue: stage tile 0 into buffer 0 ----
    {
        uint4 k0 = *(const uint4*)&K[base + (size_t)kkey0 * 64 + kd0];
        uint4 k1 = *(const uint4*)&K[base + (size_t)kkey1 * 64 + kd1];
        gload16(&V[base + (size_t)vkey0 * 64 + vd0], &Vs0[kci0 * 8]);
        gload16(&V[base + (size_t)vkey1 * 64 + vd1], &Vs0[kci1 * 8]);
        *(uint4*)(KsB0 + kbyt0) = k0;
        *(uint4*)(KsB0 + kbyt1) = k1;
    }
    __syncthreads();   // drains vmcnt(0)+lgkmcnt(0): tile 0 resident

    int cur = 0;
    for (int kt = 0; kt < 2048; kt += 64) {
        const int nxt = cur ^ 1;
        const bool more = (kt + 64) < 2048;
        char* const KsBc = KsB0 + cur * 8192;        // ptr math, not runtime idx
        const unsigned vbc = vb0 + cur * 8192;

        // ---- issue next tile's staging EARLY (hides HBM under compute) ----
        uint4 kn0, kn1;
        if (more) {
            const size_t nb = base + (size_t)(kt + 64) * 64;
            gload16(&V[nb + (size_t)vkey0 * 64 + vd0], &Vs0[nxt * 4096 + kci0 * 8]);
            gload16(&V[nb + (size_t)vkey1 * 64 + vd1], &Vs0[nxt * 4096 + kci1 * 8]);
            kn0 = *(const uint4*)&K[nb + (size_t)kkey0 * 64 + kd0];
            kn1 = *(const uint4*)&K[nb + (size_t)kkey1 * 64 + kd1];
        }

        // ---- S^T = K Q^T : s[u][kb][r] = S[q=q16][key=kb*16+4g+r] ----
        f32x4 s[2][4] = {};
#pragma unroll
        for (int kb = 0; kb < 4; ++kb) {
#pragma unroll
            for (int ks = 0; ks < 2; ++ks) {
                int key = kb * 16 + q16;
                int d0 = ks * 32 + g * 8;
                int byt = (key * 128 + d0 * 2) ^ ((key & 7) << 4);
                bf16x8 kf = *(const bf16x8*)(KsBc + byt);
                s[0][kb] = mfma16(kf, qf[0][ks], s[0][kb]);
                s[1][kb] = mfma16(kf, qf[1][ks], s[1][kb]);
            }
        }

        bf16x8 pa[2][2];
#pragma unroll
        for (int u = 0; u < 2; ++u) {
            // ---- in-lane online softmax (scale pre-folded into Q) ----
            const float* t = (const float*)&s[u][0];   // 16 values, this lane's row

            // max tree shaped for v_max3_f32 fusion
            float mx = fmaxf(t[0], t[1]);
            mx = fmaxf(fmaxf(mx, t[2]), t[3]);
            mx = fmaxf(fmaxf(mx, t[4]), t[5]);
            mx = fmaxf(fmaxf(mx, t[6]), t[7]);
            mx = fmaxf(fmaxf(mx, t[8]), t[9]);
            mx = fmaxf(fmaxf(mx, t[10]), t[11]);
            mx = fmaxf(fmaxf(mx, t[12]), t[13]);
            mx = fmaxf(fmaxf(mx, t[14]), t[15]);
            mx = fmaxf(mx, __shfl_xor(mx, 16));
            mx = fmaxf(mx, __shfl_xor(mx, 32));

            // T13 defer-rescale: only rescale when max grew past THR (log2)
            if (!__all(mx <= m_run[u] + DEFER_THR)) {
                float mn = fmaxf(m_run[u], mx);
                float fr = __builtin_amdgcn_exp2f(m_run[u] - mn);
                m_run[u] = mn;
                float fro[4];
#pragma unroll
                for (int r = 0; r < 4; ++r) fro[r] = __shfl(fr, g * 4 + r);
#pragma unroll
                for (int cb = 0; cb < 4; ++cb)
#pragma unroll
                    for (int r = 0; r < 4; ++r) o[u][cb][r] *= fro[r];
#pragma unroll
                for (int r = 0; r < 4; ++r) lacc[u][r] *= fro[r];
            }
            const float mn = m_run[u];

            unsigned w[4][2];
#pragma unroll
            for (int kb = 0; kb < 4; ++kb) {
                float p0 = __builtin_amdgcn_exp2f(t[kb * 4 + 0] - mn);
                float p1 = __builtin_amdgcn_exp2f(t[kb * 4 + 1] - mn);
                float p2 = __builtin_amdgcn_exp2f(t[kb * 4 + 2] - mn);
                float p3 = __builtin_amdgcn_exp2f(t[kb * 4 + 3] - mn);
                w[kb][0] = cvt_pk_bf16(p0, p1);
                w[kb][1] = cvt_pk_bf16(p2, p3);
            }

            // ---- P exchange: C-layout -> A-frag layout via wave-private LDS
            // (single per-wave buffer reused for u=0 and u=1: sequential+fenced)
            char* PsB = (char*)Ps[wid];
            {
                u32x4 c0 = {w[0][0], w[0][1], w[2][0], w[2][1]};
                u32x4 c1 = {w[1][0], w[1][1], w[3][0], w[3][1]};
                *(u32x4*)(PsB + ((lane * 32 + 0)  ^ ((lane & 7) << 4))) = c0;
                *(u32x4*)(PsB + ((lane * 32 + 16) ^ ((lane & 7) << 4))) = c1;
            }
            asm volatile("" ::: "memory");
            __builtin_amdgcn_sched_barrier(0);
            int s1 = q16 + 32 * (g & 1);
            int ch = (g >> 1) * 16;
            u32x4 r1 = *(const u32x4*)(PsB + ((s1 * 32 + ch) ^ ((s1 & 7) << 4)));
            u32x4 r2 = *(const u32x4*)(PsB + (((s1 + 16) * 32 + ch) ^ (((s1 + 16) & 7) << 4)));
            asm volatile("" ::: "memory");
            __builtin_amdgcn_sched_barrier(0);
            {
                u32x4 p0 = {r1.x, r1.y, r2.x, r2.y};
                u32x4 p1 = {r1.z, r1.w, r2.z, r2.w};
                pa[u][0] = __builtin_bit_cast(bf16x8, p0);
                pa[u][1] = __builtin_bit_cast(bf16x8, p1);
            }

            lacc[u] = mfma16(pa[u][0], onesb, lacc[u]);
            lacc[u] = mfma16(pa[u][1], onesb, lacc[u]);
        }

        // ---- O += P V : V via HW transpose reads (slot addressing) ----
        bf16x4 vlo[4][2], vhi[4][2];
#pragma unroll
        for (int cb = 0; cb < 4; ++cb)
#pragma unroll
            for (int ks = 0; ks < 2; ++ks) {
                unsigned a = vbc + cb * 2048 + (ks * 32 + g * 8) * 32 + q16 * 8;
                vlo[cb][ks] = trread(a);
                vhi[cb][ks] = trread(a + 128);
            }
        asm volatile("s_waitcnt lgkmcnt(0)" ::: "memory");
        __builtin_amdgcn_sched_barrier(0);
#pragma unroll
        for (int cb = 0; cb < 4; ++cb)
#pragma unroll
            for (int ks = 0; ks < 2; ++ks) {
                bf16x8 vf = __builtin_shufflevector(vlo[cb][ks], vhi[cb][ks],
                                                    0, 1, 2, 3, 4, 5, 6, 7);
                o[0][cb] = mfma16(pa[0][ks], vf, o[0][cb]);
                o[1][cb] = mfma16(pa[1][ks], vf, o[1][cb]);
            }

        // ---- write next tile's K regs into buf nxt, single barrier ----
        if (more) {
            char* const KsBn = KsB0 + nxt * 8192;
            *(uint4*)(KsBn + kbyt0) = kn0;
            *(uint4*)(KsBn + kbyt1) = kn1;
        }
        __syncthreads();   // drains vmcnt (V DMA) + lgkmcnt (K writes)
        cur = nxt;
    }

    // ---- epilogue: O /= l, write bf16 [B,N,H*D] ----
    const int b = bh >> 4, h = bh & 15;
#pragma unroll
    for (int u = 0; u < 2; ++u) {
#pragma unroll
        for (int r = 0; r < 4; ++r) {
            float inv = 1.0f / lacc[u][r];
            int row = qt * 128 + wid * 32 + u * 16 + g * 4 + r;
#pragma unroll
            for (int cb = 0; cb < 4; ++cb) {
                int col = h * 64 + cb * 16 + q16;
                O[((size_t)(b * 2048 + row)) * 1024 + col] = f2bf(o[u][cb][r] * inv);
            }
        }
    }
}

// ---------------- launch ----------------
extern "C" void kernel_launch(void* const* d_in, const int* in_sizes, int n_in,
                              void* d_out, int out_size, void* d_ws, size_t ws_size,
                              hipStream_t stream) {
    const float* x  = (const float*)d_in[0];
    const float* Wq = (const float*)d_in[1];
    const float* Wk = (const float*)d_in[2];
    const float* Wv = (const float*)d_in[3];
    const float* Wo = (const float*)d_in[4];
    const float* bo = (const float*)d_in[5];
    float* out = (float*)d_out;

    if (ws_size < (size_t)72 * 1024 * 1024) return;
    ushort* ws  = (ushort*)d_ws;
    ushort* xb  = ws;
    ushort* wt  = xb + (size_t)8 * 1024 * 1024;
    ushort* qkv = wt + (size_t)4 * 1024 * 1024;
    ushort* ao  = xb;   // reuse xb after QKV GEMM consumed it

    cast_bf16_kernel<<<8192, 256, 0, stream>>>((const float4*)x, (ushort4*)xb,
                                               2 * 1024 * 1024);
    transpose_cast_kernel<<<dim3(32, 32, 4), dim3(32, 8), 0, stream>>>(Wq, Wk, Wv, Wo, wt);
    gemm128<0><<<dim3(64, 8, 3), 256, 0, stream>>>(xb, wt, qkv, nullptr, nullptr);
    attn_kernel<<<1024, 256, 0, stream>>>(
        qkv, qkv + (size_t)8 * 1024 * 1024, qkv + (size_t)16 * 1024 * 1024, ao);
    gemm128<1><<<dim3(64, 8, 1), 256, 0, stream>>>(ao, wt + (size_t)3 * 1024 * 1024,
                                                   nullptr, out, bo);
}